// Round 8
// baseline (363.494 us; speedup 1.0000x reference)
//
#include <hip/hip_runtime.h>
#include <hip/hip_bf16.h>

#define VOCAB 30522
#define VPAD 30592   // VOCAB padded to multiple of 128 (for branch-free B staging)
#define HIDDEN 768
#define NHEADS 4
#define NHID 128
#define ROWS 2048
#define KDIM 512
#define LN_EPS 1e-12f
#define ALPHA_LR 0.01f
#define NEGV -9.0e15f
#define NTILE 239   // ceil(30522/128)

typedef __attribute__((ext_vector_type(8))) short short8;
typedef __attribute__((ext_vector_type(4))) float floatx4;
typedef __attribute__((ext_vector_type(2))) float floatx2;
typedef __attribute__((ext_vector_type(4))) unsigned short ushort4v;
typedef __attribute__((ext_vector_type(8))) unsigned short ushort8v;

static __device__ __forceinline__ unsigned short f2bf(float f) {
  unsigned int u = __float_as_uint(f);
  unsigned int r = u + 0x7fffu + ((u >> 16) & 1u);
  return (unsigned short)(r >> 16);
}

// async global->LDS, 16B per lane (dest must be wave-linear: base + lane*16)
static __device__ __forceinline__ void gload16(const unsigned short* g, unsigned short* l) {
  __builtin_amdgcn_global_load_lds(
      (const __attribute__((address_space(1))) void*)g,
      (__attribute__((address_space(3))) void*)l, 16, 0, 0);
}

// ---------------- kernel A: fused preprocessing ----------------
// blocks [0,2048):       out_W fp32 -> bf16 (+ zero pad rows)
// blocks [2048,2072):    W (4,768,128) -> Wt (512,768) bf16 transposed (LDS transpose)
// blocks [2072,4120):    embeddings + LayerNorm -> xb bf16
__global__ __launch_bounds__(256) void k_prep(const float* __restrict__ out_W,
    unsigned short* __restrict__ owb,
    const float* __restrict__ W, unsigned short* __restrict__ Wt,
    const int* __restrict__ tok, const int* __restrict__ typ,
    const float* __restrict__ tok_emb, const float* __restrict__ type_emb, const float* __restrict__ pos_emb,
    const float* __restrict__ ln_g, const float* __restrict__ ln_b, unsigned short* __restrict__ xout) {
  __shared__ unsigned short T[128][136];   // transpose staging (34.8 KB)
  __shared__ float red[8];
  int bid = blockIdx.x;
  if (bid < 2048) {
    // ---- convert out_W ----
    int n4src = (VOCAB * KDIM) / 4, n4tot = (VPAD * KDIM) / 4;
    int i = bid * 256 + threadIdx.x;
    int stride = 2048 * 256;
    for (; i < n4tot; i += stride) {
      ushort4v o = {0, 0, 0, 0};
      if (i < n4src) {
        floatx4 v = reinterpret_cast<const floatx4*>(out_W)[i];
        o.x = f2bf(v.x); o.y = f2bf(v.y); o.z = f2bf(v.z); o.w = f2bf(v.w);
      }
      reinterpret_cast<ushort4v*>(owb)[i] = o;
    }
  } else if (bid < 2072) {
    // ---- transpose W -> Wt ----
    int b = bid - 2048;
    int h = b & 3, dc = b >> 2;          // dc in 0..5 (6 chunks of 128 d)
    int tid = threadIdx.x;
    const float* Wb = W + ((long)h * HIDDEN + dc * 128) * NHID;
    #pragma unroll
    for (int q = 0; q < 16; q++) {
      int idx = q * 256 + tid;           // 0..4095 over 128d x 32 f4
      int d = idx >> 5, f4 = idx & 31;
      floatx4 v = *reinterpret_cast<const floatx4*>(&Wb[(long)d * NHID + f4 * 4]);
      #pragma unroll
      for (int j = 0; j < 4; j++) T[f4 * 4 + j][d] = f2bf(v[j]);
    }
    __syncthreads();
    int f = tid >> 1, rh = tid & 1;
    unsigned short* dst = Wt + (long)(h * 128 + f) * HIDDEN + dc * 128 + rh * 64;
    #pragma unroll
    for (int i = 0; i < 8; i++)
      *reinterpret_cast<ushort8v*>(&dst[i * 8]) =
          *reinterpret_cast<const ushort8v*>(&T[f][rh * 64 + i * 8]);
  } else {
    // ---- embeddings + LN ----
    int row = bid - 2072;
    int n = row & 255;
    int t = tok[row], ty = typ[row];
    const float* te = tok_emb + (long)t * HIDDEN;
    const float* ye = type_emb + (long)ty * HIDDEN;
    const float* pe = pos_emb + (long)n * HIDDEN;
    float v[3]; float s = 0.f, ss = 0.f;
    #pragma unroll
    for (int q = 0; q < 3; q++) {
      int d = threadIdx.x + q * 256;
      float x = te[d] + ye[d] + pe[d];
      v[q] = x; s += x; ss += x * x;
    }
    for (int off = 32; off; off >>= 1) { s += __shfl_down(s, off); ss += __shfl_down(ss, off); }
    int wid = threadIdx.x >> 6;
    if ((threadIdx.x & 63) == 0) { red[wid] = s; red[4 + wid] = ss; }
    __syncthreads();
    if (threadIdx.x == 0) {
      float a = red[0] + red[1] + red[2] + red[3];
      float b2 = red[4] + red[5] + red[6] + red[7];
      float mu = a * (1.0f / 768.0f);
      float var = b2 * (1.0f / 768.0f) - mu * mu;
      red[0] = mu; red[1] = rsqrtf(var + LN_EPS);
    }
    __syncthreads();
    float mu = red[0], rstd = red[1];
    #pragma unroll
    for (int q = 0; q < 3; q++) {
      int d = threadIdx.x + q * 256;
      xout[(long)row * HIDDEN + d] = f2bf((v[q] - mu) * rstd * ln_g[d] + ln_b[d]);
    }
  }
}

// ---------------- kernel 2: Wh = x @ W (bf16 MFMA, counted-vmcnt pipeline) ----------------
// A = xb (2048 x 768 bf16), B = Wt (512 x 768 bf16, row=output col); Wh fp32 [h][row][f]
__global__ __launch_bounds__(256) void k_wh(const unsigned short* __restrict__ A,
    const unsigned short* __restrict__ Bw, float* __restrict__ Wh) {
  int mt = blockIdx.x & 15, nt = blockIdx.x >> 4;   // 16 x 4
  int m0 = mt * 128, n0 = nt * 128;
  __shared__ __align__(16) unsigned short Al[2][128 * 64];
  __shared__ __align__(16) unsigned short Bl[2][128 * 64];
  int tid = threadIdx.x;
  int l = tid & 63, wid = tid >> 6;
  int wr = wid >> 1, wc = wid & 1;
  int lrow = l & 15, lgrp = l >> 4;
  floatx4 acc[4][4];
  #pragma unroll
  for (int i = 0; i < 4; i++)
    #pragma unroll
    for (int j = 0; j < 4; j++) acc[i][j] = (floatx4){0.f, 0.f, 0.f, 0.f};
  const unsigned short* Ab = A + (long)m0 * HIDDEN;
  const unsigned short* Bb = Bw + (long)n0 * HIDDEN;

  auto STAGE = [&](int t, int bufi) {
    #pragma unroll
    for (int q = 0; q < 4; q++) {
      int chunk = q * 256 + tid;
      int row = chunk >> 3, kp = chunk & 7, swz = kp ^ (row & 7);
      long off = (long)row * HIDDEN + t * 64 + swz * 8;
      gload16(Ab + off, &Al[bufi][chunk * 8]);
      gload16(Bb + off, &Bl[bufi][chunk * 8]);
    }
  };

  STAGE(0, 0);
  STAGE(1, 1);
  asm volatile("s_waitcnt vmcnt(8)" ::: "memory");
  __builtin_amdgcn_sched_barrier(0);
  __builtin_amdgcn_s_barrier();

  #pragma unroll
  for (int kt = 0; kt < 12; kt++) {
    int cur = kt & 1;
    short8 af[2][4], bf[2][4];
    #pragma unroll
    for (int kk = 0; kk < 2; kk++) {
      int sA = (kk * 4 + lgrp) ^ (lrow & 7);
      #pragma unroll
      for (int mi = 0; mi < 4; mi++)
        af[kk][mi] = *reinterpret_cast<const short8*>(&Al[cur][(wr * 64 + mi * 16 + lrow) * 64 + sA * 8]);
      #pragma unroll
      for (int ni = 0; ni < 4; ni++)
        bf[kk][ni] = *reinterpret_cast<const short8*>(&Bl[cur][(wc * 64 + ni * 16 + lrow) * 64 + sA * 8]);
    }
    asm volatile("s_waitcnt lgkmcnt(0)" ::: "memory");
    __builtin_amdgcn_sched_barrier(0);
    __builtin_amdgcn_s_barrier();
    __builtin_amdgcn_sched_barrier(0);
    if (kt < 10) STAGE(kt + 2, cur);
    #pragma unroll
    for (int kk = 0; kk < 2; kk++)
      #pragma unroll
      for (int mi = 0; mi < 4; mi++)
        #pragma unroll
        for (int ni = 0; ni < 4; ni++)
          acc[mi][ni] = __builtin_amdgcn_mfma_f32_16x16x32_bf16(af[kk][mi], bf[kk][ni], acc[mi][ni], 0, 0, 0);
    if (kt < 10) {
      asm volatile("s_waitcnt vmcnt(8)" ::: "memory");
    } else if (kt == 10) {
      asm volatile("s_waitcnt vmcnt(0)" ::: "memory");
    }
    __builtin_amdgcn_sched_barrier(0);
    if (kt < 11) __builtin_amdgcn_s_barrier();
  }

  #pragma unroll
  for (int mi = 0; mi < 4; mi++) {
    #pragma unroll
    for (int reg = 0; reg < 4; reg++) {
      int row = m0 + wr * 64 + mi * 16 + lgrp * 4 + reg;
      #pragma unroll
      for (int ni = 0; ni < 4; ni++) {
        int c = n0 + wc * 64 + ni * 16 + lrow;
        int h = c >> 7, f = c & 127;
        Wh[((long)h * ROWS + row) * NHID + f] = acc[mi][ni][reg];
      }
    }
  }
}

__device__ __forceinline__ unsigned char mk_flags(int t, int hwv, int tokv) {
  unsigned char fl = 0;
  if (hwv) {
    if (t == 1) fl |= 1;
    if (t == 3) fl |= 2;
    if (t == 0 || t == 2 || t == 5) fl |= 4;
    if (t == 6 || t == 4 || t == 0) fl |= 8;
  }
  if (tokv != 0) fl |= 16;
  return fl;
}

// ---------------- kernel 3: fused e1/e2 + column softmax stats ----------------
__global__ __launch_bounds__(256) void k_ecol(const int* __restrict__ tok, const int* __restrict__ typ,
    const int* __restrict__ syn, const int* __restrict__ hw,
    const float* __restrict__ Wh, const float* __restrict__ a,
    float* __restrict__ e1, float* __restrict__ e2,
    float* __restrict__ colmax, float* __restrict__ colrs) {
  int h = blockIdx.x >> 3, b = blockIdx.x & 7;
  __shared__ float av[256];
  __shared__ float E1[256]; __shared__ int SY[256]; __shared__ unsigned char FL[256];
  int tid = threadIdx.x;
  int g = b * 256 + tid;
  av[tid] = a[h * 256 + tid];
  FL[tid] = mk_flags(typ[g], hw[g], tok[g]);
  SY[tid] = syn[g];
  __syncthreads();
  const float* wr = Wh + ((long)h * ROWS + g) * NHID;
  float s1 = 0.f, s2 = 0.f;
  #pragma unroll 8
  for (int f = 0; f < 128; f++) { float w = wr[f]; s1 += w * av[f]; s2 += w * av[128 + f]; }
  e1[h * ROWS + g] = s1; e2[h * ROWS + g] = s2;
  E1[tid] = s1;
  __syncthreads();
  float e2j = s2;
  int syj = SY[tid]; unsigned char flj = FL[tid];
  bool npj = flj & 16, d1j = flj & 4, d3j = flj & 8;
  float m = -INFINITY;
  for (int i = 0; i < 256; i++) {
    float e = E1[i] + e2j;
    e = e > 0.f ? e : ALPHA_LR * e;
    unsigned char fli = FL[i];
    bool vis = (SY[i] == syj) || ((fli & 1) && d1j) || ((fli & 2) && d3j);
    float v = (vis && npj) ? e : NEGV;
    m = fmaxf(m, v);
  }
  float s = 0.f;
  for (int i = 0; i < 256; i++) {
    float e = E1[i] + e2j;
    e = e > 0.f ? e : ALPHA_LR * e;
    unsigned char fli = FL[i];
    bool vis = (SY[i] == syj) || ((fli & 1) && d1j) || ((fli & 2) && d3j);
    float v = (vis && npj) ? e : NEGV;
    s += __expf(v - m);
  }
  int idx = (h * 8 + b) * 256 + tid;
  colmax[idx] = m;
  colrs[idx] = 1.0f / s;
}

// ---------------- kernel 4: hp = elu(att @ Wh) -> cat (bf16) ----------------
__global__ __launch_bounds__(256) void k_att(const int* __restrict__ tok, const int* __restrict__ typ,
    const int* __restrict__ syn, const int* __restrict__ hw,
    const float* __restrict__ e1, const float* __restrict__ e2,
    const float* __restrict__ colmax, const float* __restrict__ colrs,
    const float* __restrict__ Wh, unsigned short* __restrict__ cat) {
  int chunk = blockIdx.x & 7; int hb = blockIdx.x >> 3;
  int h = hb >> 3, b = hb & 7;
  __shared__ float E2[256], CM[256], CR[256];
  __shared__ int SY[256]; __shared__ unsigned char FL[256];
  __shared__ float WJ[64][128];
  int tid = threadIdx.x;
  {
    int g = b * 256 + tid;
    FL[tid] = mk_flags(typ[g], hw[g], tok[g]);
    E2[tid] = e2[h * ROWS + g];
    CM[tid] = colmax[hb * 256 + tid];
    CR[tid] = colrs[hb * 256 + tid];
    SY[tid] = syn[g];
  }
  __syncthreads();
  int i = chunk * 32 + (tid >> 3);
  int gi = b * 256 + i;
  float e1i = e1[h * ROWS + gi];
  unsigned char fli = FL[i];
  bool s1i = fli & 1, s3i = fli & 2;
  int syni = SY[i];
  int f0 = tid & 7;
  floatx4 acc4[4];
  #pragma unroll
  for (int k2 = 0; k2 < 4; k2++) acc4[k2] = (floatx4){0.f, 0.f, 0.f, 0.f};
  for (int j0 = 0; j0 < 256; j0 += 64) {
    #pragma unroll
    for (int q = 0; q < 8; q++) {
      int e = tid + q * 256;          // 0..2047
      int j = e >> 5, f4 = e & 31;
      *reinterpret_cast<floatx4*>(&WJ[j][f4 * 4]) =
          *reinterpret_cast<const floatx4*>(&Wh[((long)h * ROWS + b * 256 + j0 + j) * NHID + f4 * 4]);
    }
    __syncthreads();
    for (int j = 0; j < 64; j++) {
      int jj = j0 + j;
      unsigned char flj = FL[jj];
      bool vis = (syni == SY[jj]) || (s1i && (flj & 4)) || (s3i && (flj & 8));
      bool msk = vis && (flj & 16);
      float ev = e1i + E2[jj];
      ev = ev > 0.f ? ev : ALPHA_LR * ev;
      float v = msk ? ev : NEGV;
      float w = __expf(v - CM[jj]) * CR[jj];
      #pragma unroll
      for (int k2 = 0; k2 < 4; k2++) {
        floatx4 wv = *reinterpret_cast<const floatx4*>(&WJ[j][(f0 + 8 * k2) * 4]);
        acc4[k2] += wv * w;
      }
    }
    __syncthreads();
  }
  ushort4v* cr4 = reinterpret_cast<ushort4v*>(cat + (long)gi * KDIM + h * NHID);
  #pragma unroll
  for (int k2 = 0; k2 < 4; k2++) {
    ushort4v o4;
    #pragma unroll
    for (int e = 0; e < 4; e++) {
      float v = acc4[k2][e];
      v = v > 0.f ? v : __expf(v) - 1.f;
      o4[e] = f2bf(v);
    }
    cr4[f0 + 8 * k2] = o4;
  }
}

// ---------------- kernel 5: big GEMM (bf16 MFMA, 256x128 tile, 8 waves, counted-vmcnt) ----------------
// writes bf16 elu'd logits into the first half of each output row's fp32 slot
__global__ __launch_bounds__(512) void k_gemm(const unsigned short* __restrict__ A,
    const unsigned short* __restrict__ Bw, const float* __restrict__ bias,
    unsigned short* __restrict__ otmp) {
  // bijective XCD swizzle: 1912 blocks, 1912 % 8 == 0, chunk = 239 per XCD
  int bid = blockIdx.x;
  int lin = (bid & 7) * 239 + (bid >> 3);
  int mt = lin & 7, nt = lin >> 3;           // mt-fast: 8 consecutive lin share B-panel window
  int m0 = mt * 256, n0 = nt * 128;
  __shared__ __align__(16) unsigned short Al[2][256 * 64];   // 64 KB
  __shared__ __align__(16) unsigned short Bl[2][128 * 64];   // 32 KB
  int tid = threadIdx.x;
  int l = tid & 63, wid = tid >> 6;          // 8 waves
  int wr = wid >> 1, wc = wid & 1;           // 4 x 2 -> per-wave 64 rows x 64 cols
  int lrow = l & 15, lgrp = l >> 4;
  floatx4 acc[4][4];
  #pragma unroll
  for (int i = 0; i < 4; i++)
    #pragma unroll
    for (int j = 0; j < 4; j++) acc[i][j] = (floatx4){0.f, 0.f, 0.f, 0.f};
  const unsigned short* Ab = A + (long)m0 * KDIM;
  const unsigned short* Bb = Bw + (long)n0 * KDIM;

  // stage tile t: A 256x64 (4 loads/thread), B 128x64 (2 loads/thread) -> 6 VMEM inst/thread
  auto STAGE = [&](int t, int bufi) {
    #pragma unroll
    for (int q = 0; q < 4; q++) {
      int chunk = q * 512 + tid;             // 0..2047
      int row = chunk >> 3, kp = chunk & 7, swz = kp ^ (row & 7);
      long off = (long)row * KDIM + t * 64 + swz * 8;
      gload16(Ab + off, &Al[bufi][chunk * 8]);
    }
    #pragma unroll
    for (int q = 0; q < 2; q++) {
      int chunk = q * 512 + tid;             // 0..1023
      int row = chunk >> 3, kp = chunk & 7, swz = kp ^ (row & 7);
      long off = (long)row * KDIM + t * 64 + swz * 8;
      gload16(Bb + off, &Bl[bufi][chunk * 8]);
    }
  };

  STAGE(0, 0);
  STAGE(1, 1);
  asm volatile("s_waitcnt vmcnt(6)" ::: "memory");   // tile 0 landed; tile 1 (6 loads) in flight
  __builtin_amdgcn_sched_barrier(0);
  __builtin_amdgcn_s_barrier();

  #pragma unroll
  for (int kt = 0; kt < 8; kt++) {
    int cur = kt & 1;
    short8 af[2][4], bf[2][4];
    #pragma unroll
    for (int kk = 0; kk < 2; kk++) {
      int sA = (kk * 4 + lgrp) ^ (lrow & 7);
      #pragma unroll
      for (int mi = 0; mi < 4; mi++)
        af[kk][mi] = *reinterpret_cast<const short8*>(&Al[cur][(wr * 64 + mi * 16 + lrow) * 64 + sA * 8]);
      #pragma unroll
      for (int ni = 0; ni < 4; ni++)
        bf[kk][ni] = *reinterpret_cast<const short8*>(&Bl[cur][(wc * 64 + ni * 16 + lrow) * 64 + sA * 8]);
    }
    asm volatile("s_waitcnt lgkmcnt(0)" ::: "memory");  // my reads of buf[cur] complete
    __builtin_amdgcn_sched_barrier(0);
    __builtin_amdgcn_s_barrier();                       // ALL waves done reading buf[cur]
    __builtin_amdgcn_sched_barrier(0);
    if (kt < 6) STAGE(kt + 2, cur);                     // overwrite buf[cur] with tile kt+2
    #pragma unroll
    for (int kk = 0; kk < 2; kk++)
      #pragma unroll
      for (int mi = 0; mi < 4; mi++)
        #pragma unroll
        for (int ni = 0; ni < 4; ni++)
          acc[mi][ni] = __builtin_amdgcn_mfma_f32_16x16x32_bf16(af[kk][mi], bf[kk][ni], acc[mi][ni], 0, 0, 0);
    if (kt < 6) {
      asm volatile("s_waitcnt vmcnt(6)" ::: "memory");  // tile kt+1 landed; kt+2 (6 loads) in flight
    } else if (kt == 6) {
      asm volatile("s_waitcnt vmcnt(0)" ::: "memory");  // tail: tile 7 landed
    }
    __builtin_amdgcn_sched_barrier(0);
    if (kt < 7) __builtin_amdgcn_s_barrier();
  }

  // epilogue: bias + elu + bf16 store only (lse handled downstream in k_sub)
  float bcol[4]; bool valid[4]; int cols[4];
  #pragma unroll
  for (int ni = 0; ni < 4; ni++) {
    int c = n0 + wc * 64 + ni * 16 + lrow;
    cols[ni] = c; valid[ni] = c < VOCAB;
    bcol[ni] = valid[ni] ? bias[c] : 0.f;
  }
  #pragma unroll
  for (int mi = 0; mi < 4; mi++) {
    #pragma unroll
    for (int reg = 0; reg < 4; reg++) {
      int row = m0 + wr * 64 + mi * 16 + lgrp * 4 + reg;
      unsigned short* orow = otmp + (long)row * 2 * VOCAB;
      #pragma unroll
      for (int ni = 0; ni < 4; ni++) {
        if (valid[ni]) {
          float z = acc[mi][ni][reg] + bcol[ni];
          float o = z > 0.f ? z : __expf(z) - 1.f;
          orow[cols[ni]] = f2bf(o);
        }
      }
    }
  }
}

// ---------------- kernel 6: in-place bf16 -> (fp32 - lse) with in-block lse ----------------
__global__ __launch_bounds__(1024) void k_sub(float* __restrict__ out) {
  int row = blockIdx.x;
  float* rb = out + (long)row * VOCAB;
  const unsigned int* src = reinterpret_cast<const unsigned int*>(rb);  // bf16 pairs
  int tid = threadIdx.x;
  unsigned int v[15];
  float se = 0.f;
  #pragma unroll
  for (int i = 0; i < 15; i++) {
    int p = tid + i * 1024;
    v[i] = (p < VOCAB / 2) ? src[p] : 0u;
  }
  #pragma unroll
  for (int i = 0; i < 15; i++) {
    int p = tid + i * 1024;
    if (p < VOCAB / 2) {
      unsigned int u = v[i];
      float lo = __uint_as_float((u & 0xffffu) << 16);
      float hi = __uint_as_float(u & 0xffff0000u);
      se += __expf(lo) + __expf(hi);
    }
  }
  #pragma unroll
  for (int off = 32; off; off >>= 1) se += __shfl_xor(se, off);
  __shared__ float red[16];
  int wid = tid >> 6;
  if ((tid & 63) == 0) red[wid] = se;
  __syncthreads();
  if (tid < 16) {
    float r = red[tid];
    #pragma unroll
    for (int off = 8; off; off >>= 1) r += __shfl_xor(r, off);
    if (tid == 0) red[0] = logf(r);
  }
  __syncthreads();
  float L = red[0];
  floatx2* dst = reinterpret_cast<floatx2*>(rb);
  #pragma unroll
  for (int i = 0; i < 15; i++) {
    int p = tid + i * 1024;
    if (p < VOCAB / 2) {
      unsigned int u = v[i];
      float lo = __uint_as_float((u & 0xffffu) << 16);
      float hi = __uint_as_float(u & 0xffff0000u);
      floatx2 o; o.x = lo - L; o.y = hi - L;
      dst[p] = o;
    }
  }
}

extern "C" void kernel_launch(void* const* d_in, const int* in_sizes, int n_in,
                              void* d_out, int out_size, void* d_ws, size_t ws_size,
                              hipStream_t stream) {
  const int* tok = (const int*)d_in[0];
  const int* typ = (const int*)d_in[1];
  const int* syn = (const int*)d_in[2];
  const int* hw  = (const int*)d_in[3];
  const float* tok_emb  = (const float*)d_in[4];
  const float* type_emb = (const float*)d_in[5];
  const float* pos_emb  = (const float*)d_in[6];
  const float* ln_g = (const float*)d_in[7];
  const float* ln_b = (const float*)d_in[8];
  const float* W    = (const float*)d_in[9];
  const float* a    = (const float*)d_in[10];
  const float* out_W = (const float*)d_in[11];
  const float* out_b = (const float*)d_in[12];
  float* out = (float*)d_out;
  char* ws = (char*)d_ws;
  // ws layout (bytes)
  unsigned short* xb = (unsigned short*)(ws + 0);          // 2048*768*2 = 3145728
  float* Wh  = (float*)(ws + 3145728);                     // 4*2048*128*4 = 4194304
  float* e1  = (float*)(ws + 7340032);                     // 32768
  float* e2  = (float*)(ws + 7372800);                     // 32768
  float* cm  = (float*)(ws + 7405568);                     // 32768
  float* cs  = (float*)(ws + 7438336);                     // 32768
  unsigned short* cat = (unsigned short*)(ws + 7471104);   // 2048*512*2 = 2097152
  unsigned short* Wt  = (unsigned short*)(ws + 9568256);   // 512*768*2 = 786432
  unsigned short* owb = (unsigned short*)(ws + 10354688);  // VPAD*512*2 = 31326208

  k_prep<<<4120, 256, 0, stream>>>(out_W, owb, W, Wt, tok, typ,
                                   tok_emb, type_emb, pos_emb, ln_g, ln_b, xb);
  k_wh<<<64, 256, 0, stream>>>(xb, Wt, Wh);
  k_ecol<<<32, 256, 0, stream>>>(tok, typ, syn, hw, Wh, a, e1, e2, cm, cs);
  k_att<<<256, 256, 0, stream>>>(tok, typ, syn, hw, e1, e2, cm, cs, Wh, cat);
  k_gemm<<<8 * NTILE, 512, 0, stream>>>(cat, owb, out_b, (unsigned short*)out);
  k_sub<<<2048, 1024, 0, stream>>>(out);
}

// Round 9
// 302.715 us; speedup vs baseline: 1.2008x; 1.2008x over previous
//
#include <hip/hip_runtime.h>
#include <hip/hip_bf16.h>

#define VOCAB 30522
#define VPAD 30592   // VOCAB padded to multiple of 128 (for branch-free B staging)
#define HIDDEN 768
#define NHEADS 4
#define NHID 128
#define ROWS 2048
#define KDIM 512
#define LN_EPS 1e-12f
#define ALPHA_LR 0.01f
#define NEGV -9.0e15f
#define NTILE 239   // ceil(30522/128)

typedef __attribute__((ext_vector_type(8))) short short8;
typedef __attribute__((ext_vector_type(4))) float floatx4;
typedef __attribute__((ext_vector_type(2))) float floatx2;
typedef __attribute__((ext_vector_type(4))) unsigned short ushort4v;
typedef __attribute__((ext_vector_type(8))) unsigned short ushort8v;

static __device__ __forceinline__ unsigned short f2bf(float f) {
  unsigned int u = __float_as_uint(f);
  unsigned int r = u + 0x7fffu + ((u >> 16) & 1u);
  return (unsigned short)(r >> 16);
}

// async global->LDS, 16B per lane (dest must be wave-linear: base + lane*16)
static __device__ __forceinline__ void gload16(const unsigned short* g, unsigned short* l) {
  __builtin_amdgcn_global_load_lds(
      (const __attribute__((address_space(1))) void*)g,
      (__attribute__((address_space(3))) void*)l, 16, 0, 0);
}

// ---------------- kernel A: fused preprocessing ----------------
// blocks [0,2048):       out_W fp32 -> bf16 (+ zero pad rows)
// blocks [2048,2072):    W (4,768,128) -> Wt (512,768) bf16 transposed (LDS transpose)
// blocks [2072,4120):    embeddings + LayerNorm -> xb bf16
__global__ __launch_bounds__(256) void k_prep(const float* __restrict__ out_W,
    unsigned short* __restrict__ owb,
    const float* __restrict__ W, unsigned short* __restrict__ Wt,
    const int* __restrict__ tok, const int* __restrict__ typ,
    const float* __restrict__ tok_emb, const float* __restrict__ type_emb, const float* __restrict__ pos_emb,
    const float* __restrict__ ln_g, const float* __restrict__ ln_b, unsigned short* __restrict__ xout) {
  __shared__ unsigned short T[128][136];   // transpose staging (34.8 KB)
  __shared__ float red[8];
  int bid = blockIdx.x;
  if (bid < 2048) {
    // ---- convert out_W ----
    int n4src = (VOCAB * KDIM) / 4, n4tot = (VPAD * KDIM) / 4;
    int i = bid * 256 + threadIdx.x;
    int stride = 2048 * 256;
    for (; i < n4tot; i += stride) {
      ushort4v o = {0, 0, 0, 0};
      if (i < n4src) {
        floatx4 v = reinterpret_cast<const floatx4*>(out_W)[i];
        o.x = f2bf(v.x); o.y = f2bf(v.y); o.z = f2bf(v.z); o.w = f2bf(v.w);
      }
      reinterpret_cast<ushort4v*>(owb)[i] = o;
    }
  } else if (bid < 2072) {
    // ---- transpose W -> Wt ----
    int b = bid - 2048;
    int h = b & 3, dc = b >> 2;          // dc in 0..5 (6 chunks of 128 d)
    int tid = threadIdx.x;
    const float* Wb = W + ((long)h * HIDDEN + dc * 128) * NHID;
    #pragma unroll
    for (int q = 0; q < 16; q++) {
      int idx = q * 256 + tid;           // 0..4095 over 128d x 32 f4
      int d = idx >> 5, f4 = idx & 31;
      floatx4 v = *reinterpret_cast<const floatx4*>(&Wb[(long)d * NHID + f4 * 4]);
      #pragma unroll
      for (int j = 0; j < 4; j++) T[f4 * 4 + j][d] = f2bf(v[j]);
    }
    __syncthreads();
    int f = tid >> 1, rh = tid & 1;
    unsigned short* dst = Wt + (long)(h * 128 + f) * HIDDEN + dc * 128 + rh * 64;
    #pragma unroll
    for (int i = 0; i < 8; i++)
      *reinterpret_cast<ushort8v*>(&dst[i * 8]) =
          *reinterpret_cast<const ushort8v*>(&T[f][rh * 64 + i * 8]);
  } else {
    // ---- embeddings + LN ----
    int row = bid - 2072;
    int n = row & 255;
    int t = tok[row], ty = typ[row];
    const float* te = tok_emb + (long)t * HIDDEN;
    const float* ye = type_emb + (long)ty * HIDDEN;
    const float* pe = pos_emb + (long)n * HIDDEN;
    float v[3]; float s = 0.f, ss = 0.f;
    #pragma unroll
    for (int q = 0; q < 3; q++) {
      int d = threadIdx.x + q * 256;
      float x = te[d] + ye[d] + pe[d];
      v[q] = x; s += x; ss += x * x;
    }
    for (int off = 32; off; off >>= 1) { s += __shfl_down(s, off); ss += __shfl_down(ss, off); }
    int wid = threadIdx.x >> 6;
    if ((threadIdx.x & 63) == 0) { red[wid] = s; red[4 + wid] = ss; }
    __syncthreads();
    if (threadIdx.x == 0) {
      float a = red[0] + red[1] + red[2] + red[3];
      float b2 = red[4] + red[5] + red[6] + red[7];
      float mu = a * (1.0f / 768.0f);
      float var = b2 * (1.0f / 768.0f) - mu * mu;
      red[0] = mu; red[1] = rsqrtf(var + LN_EPS);
    }
    __syncthreads();
    float mu = red[0], rstd = red[1];
    #pragma unroll
    for (int q = 0; q < 3; q++) {
      int d = threadIdx.x + q * 256;
      xout[(long)row * HIDDEN + d] = f2bf((v[q] - mu) * rstd * ln_g[d] + ln_b[d]);
    }
  }
}

// ---------------- kernel 2: Wh = x @ W (bf16 MFMA, counted-vmcnt pipeline) ----------------
// A = xb (2048 x 768 bf16), B = Wt (512 x 768 bf16, row=output col); Wh fp32 [h][row][f]
__global__ __launch_bounds__(256) void k_wh(const unsigned short* __restrict__ A,
    const unsigned short* __restrict__ Bw, float* __restrict__ Wh) {
  int mt = blockIdx.x & 15, nt = blockIdx.x >> 4;   // 16 x 4
  int m0 = mt * 128, n0 = nt * 128;
  __shared__ __align__(16) unsigned short Al[2][128 * 64];
  __shared__ __align__(16) unsigned short Bl[2][128 * 64];
  int tid = threadIdx.x;
  int l = tid & 63, wid = tid >> 6;
  int wr = wid >> 1, wc = wid & 1;
  int lrow = l & 15, lgrp = l >> 4;
  floatx4 acc[4][4];
  #pragma unroll
  for (int i = 0; i < 4; i++)
    #pragma unroll
    for (int j = 0; j < 4; j++) acc[i][j] = (floatx4){0.f, 0.f, 0.f, 0.f};
  const unsigned short* Ab = A + (long)m0 * HIDDEN;
  const unsigned short* Bb = Bw + (long)n0 * HIDDEN;

  auto STAGE = [&](int t, int bufi) {
    #pragma unroll
    for (int q = 0; q < 4; q++) {
      int chunk = q * 256 + tid;
      int row = chunk >> 3, kp = chunk & 7, swz = kp ^ (row & 7);
      long off = (long)row * HIDDEN + t * 64 + swz * 8;
      gload16(Ab + off, &Al[bufi][chunk * 8]);
      gload16(Bb + off, &Bl[bufi][chunk * 8]);
    }
  };

  STAGE(0, 0);
  STAGE(1, 1);
  asm volatile("s_waitcnt vmcnt(8)" ::: "memory");
  __builtin_amdgcn_sched_barrier(0);
  __builtin_amdgcn_s_barrier();

  #pragma unroll
  for (int kt = 0; kt < 12; kt++) {
    int cur = kt & 1;
    short8 af[2][4], bf[2][4];
    #pragma unroll
    for (int kk = 0; kk < 2; kk++) {
      int sA = (kk * 4 + lgrp) ^ (lrow & 7);
      #pragma unroll
      for (int mi = 0; mi < 4; mi++)
        af[kk][mi] = *reinterpret_cast<const short8*>(&Al[cur][(wr * 64 + mi * 16 + lrow) * 64 + sA * 8]);
      #pragma unroll
      for (int ni = 0; ni < 4; ni++)
        bf[kk][ni] = *reinterpret_cast<const short8*>(&Bl[cur][(wc * 64 + ni * 16 + lrow) * 64 + sA * 8]);
    }
    asm volatile("s_waitcnt lgkmcnt(0)" ::: "memory");
    __builtin_amdgcn_sched_barrier(0);
    __builtin_amdgcn_s_barrier();
    __builtin_amdgcn_sched_barrier(0);
    if (kt < 10) STAGE(kt + 2, cur);
    #pragma unroll
    for (int kk = 0; kk < 2; kk++)
      #pragma unroll
      for (int mi = 0; mi < 4; mi++)
        #pragma unroll
        for (int ni = 0; ni < 4; ni++)
          acc[mi][ni] = __builtin_amdgcn_mfma_f32_16x16x32_bf16(af[kk][mi], bf[kk][ni], acc[mi][ni], 0, 0, 0);
    if (kt < 10) {
      asm volatile("s_waitcnt vmcnt(8)" ::: "memory");
    } else if (kt == 10) {
      asm volatile("s_waitcnt vmcnt(0)" ::: "memory");
    }
    __builtin_amdgcn_sched_barrier(0);
    if (kt < 11) __builtin_amdgcn_s_barrier();
  }

  #pragma unroll
  for (int mi = 0; mi < 4; mi++) {
    #pragma unroll
    for (int reg = 0; reg < 4; reg++) {
      int row = m0 + wr * 64 + mi * 16 + lgrp * 4 + reg;
      #pragma unroll
      for (int ni = 0; ni < 4; ni++) {
        int c = n0 + wc * 64 + ni * 16 + lrow;
        int h = c >> 7, f = c & 127;
        Wh[((long)h * ROWS + row) * NHID + f] = acc[mi][ni][reg];
      }
    }
  }
}

__device__ __forceinline__ unsigned char mk_flags(int t, int hwv, int tokv) {
  unsigned char fl = 0;
  if (hwv) {
    if (t == 1) fl |= 1;
    if (t == 3) fl |= 2;
    if (t == 0 || t == 2 || t == 5) fl |= 4;
    if (t == 6 || t == 4 || t == 0) fl |= 8;
  }
  if (tokv != 0) fl |= 16;
  return fl;
}

// ---------------- kernel 3: fused e1/e2 + column softmax stats ----------------
__global__ __launch_bounds__(256) void k_ecol(const int* __restrict__ tok, const int* __restrict__ typ,
    const int* __restrict__ syn, const int* __restrict__ hw,
    const float* __restrict__ Wh, const float* __restrict__ a,
    float* __restrict__ e1, float* __restrict__ e2,
    float* __restrict__ colmax, float* __restrict__ colrs) {
  int h = blockIdx.x >> 3, b = blockIdx.x & 7;
  __shared__ float av[256];
  __shared__ float E1[256]; __shared__ int SY[256]; __shared__ unsigned char FL[256];
  int tid = threadIdx.x;
  int g = b * 256 + tid;
  av[tid] = a[h * 256 + tid];
  FL[tid] = mk_flags(typ[g], hw[g], tok[g]);
  SY[tid] = syn[g];
  __syncthreads();
  const float* wr = Wh + ((long)h * ROWS + g) * NHID;
  float s1 = 0.f, s2 = 0.f;
  #pragma unroll 8
  for (int f = 0; f < 128; f++) { float w = wr[f]; s1 += w * av[f]; s2 += w * av[128 + f]; }
  e1[h * ROWS + g] = s1; e2[h * ROWS + g] = s2;
  E1[tid] = s1;
  __syncthreads();
  float e2j = s2;
  int syj = SY[tid]; unsigned char flj = FL[tid];
  bool npj = flj & 16, d1j = flj & 4, d3j = flj & 8;
  float m = -INFINITY;
  for (int i = 0; i < 256; i++) {
    float e = E1[i] + e2j;
    e = e > 0.f ? e : ALPHA_LR * e;
    unsigned char fli = FL[i];
    bool vis = (SY[i] == syj) || ((fli & 1) && d1j) || ((fli & 2) && d3j);
    float v = (vis && npj) ? e : NEGV;
    m = fmaxf(m, v);
  }
  float s = 0.f;
  for (int i = 0; i < 256; i++) {
    float e = E1[i] + e2j;
    e = e > 0.f ? e : ALPHA_LR * e;
    unsigned char fli = FL[i];
    bool vis = (SY[i] == syj) || ((fli & 1) && d1j) || ((fli & 2) && d3j);
    float v = (vis && npj) ? e : NEGV;
    s += __expf(v - m);
  }
  int idx = (h * 8 + b) * 256 + tid;
  colmax[idx] = m;
  colrs[idx] = 1.0f / s;
}

// ---------------- kernel 4: hp = elu(att @ Wh) -> cat (bf16) ----------------
__global__ __launch_bounds__(256) void k_att(const int* __restrict__ tok, const int* __restrict__ typ,
    const int* __restrict__ syn, const int* __restrict__ hw,
    const float* __restrict__ e1, const float* __restrict__ e2,
    const float* __restrict__ colmax, const float* __restrict__ colrs,
    const float* __restrict__ Wh, unsigned short* __restrict__ cat) {
  int chunk = blockIdx.x & 7; int hb = blockIdx.x >> 3;
  int h = hb >> 3, b = hb & 7;
  __shared__ float E2[256], CM[256], CR[256];
  __shared__ int SY[256]; __shared__ unsigned char FL[256];
  __shared__ float WJ[64][128];
  int tid = threadIdx.x;
  {
    int g = b * 256 + tid;
    FL[tid] = mk_flags(typ[g], hw[g], tok[g]);
    E2[tid] = e2[h * ROWS + g];
    CM[tid] = colmax[hb * 256 + tid];
    CR[tid] = colrs[hb * 256 + tid];
    SY[tid] = syn[g];
  }
  __syncthreads();
  int i = chunk * 32 + (tid >> 3);
  int gi = b * 256 + i;
  float e1i = e1[h * ROWS + gi];
  unsigned char fli = FL[i];
  bool s1i = fli & 1, s3i = fli & 2;
  int syni = SY[i];
  int f0 = tid & 7;
  floatx4 acc4[4];
  #pragma unroll
  for (int k2 = 0; k2 < 4; k2++) acc4[k2] = (floatx4){0.f, 0.f, 0.f, 0.f};
  for (int j0 = 0; j0 < 256; j0 += 64) {
    #pragma unroll
    for (int q = 0; q < 8; q++) {
      int e = tid + q * 256;          // 0..2047
      int j = e >> 5, f4 = e & 31;
      *reinterpret_cast<floatx4*>(&WJ[j][f4 * 4]) =
          *reinterpret_cast<const floatx4*>(&Wh[((long)h * ROWS + b * 256 + j0 + j) * NHID + f4 * 4]);
    }
    __syncthreads();
    for (int j = 0; j < 64; j++) {
      int jj = j0 + j;
      unsigned char flj = FL[jj];
      bool vis = (syni == SY[jj]) || (s1i && (flj & 4)) || (s3i && (flj & 8));
      bool msk = vis && (flj & 16);
      float ev = e1i + E2[jj];
      ev = ev > 0.f ? ev : ALPHA_LR * ev;
      float v = msk ? ev : NEGV;
      float w = __expf(v - CM[jj]) * CR[jj];
      #pragma unroll
      for (int k2 = 0; k2 < 4; k2++) {
        floatx4 wv = *reinterpret_cast<const floatx4*>(&WJ[j][(f0 + 8 * k2) * 4]);
        acc4[k2] += wv * w;
      }
    }
    __syncthreads();
  }
  ushort4v* cr4 = reinterpret_cast<ushort4v*>(cat + (long)gi * KDIM + h * NHID);
  #pragma unroll
  for (int k2 = 0; k2 < 4; k2++) {
    ushort4v o4;
    #pragma unroll
    for (int e = 0; e < 4; e++) {
      float v = acc4[k2][e];
      v = v > 0.f ? v : __expf(v) - 1.f;
      o4[e] = f2bf(v);
    }
    cr4[f0 + 8 * k2] = o4;
  }
}

// ---------------- kernel 5: big GEMM (bf16 MFMA, 128x128, counted-vmcnt, LDS-staged epilogue) ----------------
// writes bf16 elu'd logits into the first half of each output row's fp32 slot
__global__ __launch_bounds__(256) void k_gemm(const unsigned short* __restrict__ A,
    const unsigned short* __restrict__ Bw, const float* __restrict__ bias,
    unsigned short* __restrict__ otmp) {
  // bijective XCD swizzle: 3824 blocks, 3824 % 8 == 0
  int bid = blockIdx.x;
  bid = (bid & 7) * ((16 * NTILE) >> 3) + (bid >> 3);
  int mt = bid & 15, nt = bid >> 4;
  int m0 = mt * 128, n0 = nt * 128;
  // LDS: staging buffers (64 KB) overlaid with C epilogue tile [128][136] (34.8 KB)
  __shared__ __align__(16) char smem[65536];
  unsigned short (*Al)[128 * 64] = reinterpret_cast<unsigned short (*)[128 * 64]>(smem);
  unsigned short (*Bl)[128 * 64] = reinterpret_cast<unsigned short (*)[128 * 64]>(smem + 32768);
  unsigned short* Cl = reinterpret_cast<unsigned short*>(smem);
  int tid = threadIdx.x;
  int l = tid & 63, wid = tid >> 6;
  int wr = wid >> 1, wc = wid & 1;
  int lrow = l & 15, lgrp = l >> 4;
  floatx4 acc[4][4];
  #pragma unroll
  for (int i = 0; i < 4; i++)
    #pragma unroll
    for (int j = 0; j < 4; j++) acc[i][j] = (floatx4){0.f, 0.f, 0.f, 0.f};
  const unsigned short* Ab = A + (long)m0 * KDIM;
  const unsigned short* Bb = Bw + (long)n0 * KDIM;

  auto STAGE = [&](int t, int bufi) {
    #pragma unroll
    for (int q = 0; q < 4; q++) {
      int chunk = q * 256 + tid;
      int row = chunk >> 3, kp = chunk & 7, swz = kp ^ (row & 7);
      long off = (long)row * KDIM + t * 64 + swz * 8;
      gload16(Ab + off, &Al[bufi][chunk * 8]);
      gload16(Bb + off, &Bl[bufi][chunk * 8]);
    }
  };

  STAGE(0, 0);
  STAGE(1, 1);
  asm volatile("s_waitcnt vmcnt(8)" ::: "memory");   // tile 0 landed; tile 1 in flight
  __builtin_amdgcn_sched_barrier(0);
  __builtin_amdgcn_s_barrier();

  #pragma unroll
  for (int kt = 0; kt < 8; kt++) {
    int cur = kt & 1;
    short8 af[2][4], bf[2][4];
    #pragma unroll
    for (int kk = 0; kk < 2; kk++) {
      int sA = (kk * 4 + lgrp) ^ (lrow & 7);
      #pragma unroll
      for (int mi = 0; mi < 4; mi++)
        af[kk][mi] = *reinterpret_cast<const short8*>(&Al[cur][(wr * 64 + mi * 16 + lrow) * 64 + sA * 8]);
      #pragma unroll
      for (int ni = 0; ni < 4; ni++)
        bf[kk][ni] = *reinterpret_cast<const short8*>(&Bl[cur][(wc * 64 + ni * 16 + lrow) * 64 + sA * 8]);
    }
    asm volatile("s_waitcnt lgkmcnt(0)" ::: "memory");  // my reads of buf[cur] complete
    __builtin_amdgcn_sched_barrier(0);
    __builtin_amdgcn_s_barrier();                       // ALL waves done reading buf[cur]
    __builtin_amdgcn_sched_barrier(0);
    if (kt < 6) STAGE(kt + 2, cur);                     // overwrite buf[cur] with tile kt+2
    #pragma unroll
    for (int kk = 0; kk < 2; kk++)
      #pragma unroll
      for (int mi = 0; mi < 4; mi++)
        #pragma unroll
        for (int ni = 0; ni < 4; ni++)
          acc[mi][ni] = __builtin_amdgcn_mfma_f32_16x16x32_bf16(af[kk][mi], bf[kk][ni], acc[mi][ni], 0, 0, 0);
    if (kt < 6) {
      asm volatile("s_waitcnt vmcnt(8)" ::: "memory");  // tile kt+1 landed; kt+2 in flight
    } else if (kt == 6) {
      asm volatile("s_waitcnt vmcnt(0)" ::: "memory");  // tail: tile 7 landed
    }
    __builtin_amdgcn_sched_barrier(0);
    if (kt < 7) __builtin_amdgcn_s_barrier();
  }
  // NOTE: after the kt=7 barrier (post-lgkmcnt), no wave reads Al/Bl again ->
  // safe to overwrite the stage LDS with the C tile.

  // epilogue phase 1: bias + elu -> bf16 into Cl[128][136] (local rows/cols of this tile)
  float bcol[4];
  #pragma unroll
  for (int ni = 0; ni < 4; ni++) {
    int c = n0 + wc * 64 + ni * 16 + lrow;
    bcol[ni] = (c < VOCAB) ? bias[c] : 0.f;   // pad cols: B rows are zero -> z=0 -> elu=0
  }
  #pragma unroll
  for (int mi = 0; mi < 4; mi++)
    #pragma unroll
    for (int ni = 0; ni < 4; ni++)
      #pragma unroll
      for (int reg = 0; reg < 4; reg++) {
        int r = wr * 64 + mi * 16 + lgrp * 4 + reg;
        int c = wc * 64 + ni * 16 + lrow;
        float z = acc[mi][ni][reg] + bcol[ni];
        float o = z > 0.f ? z : __expf(z) - 1.f;
        Cl[r * 136 + c] = f2bf(o);
      }
  __syncthreads();
  // epilogue phase 2: coalesced stores — 16 threads/row x 16B, 256B contiguous per row
  #pragma unroll
  for (int it = 0; it < 8; it++) {
    int r = it * 16 + (tid >> 4);
    int c = (tid & 15) * 8;
    int gc = n0 + c;
    ushort8v v = *reinterpret_cast<const ushort8v*>(&Cl[r * 136 + c]);
    unsigned short* orow = otmp + (long)(m0 + r) * 2 * VOCAB;
    if (gc + 8 <= VOCAB) {
      *reinterpret_cast<ushort8v*>(orow + gc) = v;
    } else {
      #pragma unroll
      for (int e = 0; e < 8; e++)
        if (gc + e < VOCAB) orow[gc + e] = v[e];
    }
  }
}

// ---------------- kernel 6: in-place bf16 -> (fp32 - lse) with in-block lse ----------------
__global__ __launch_bounds__(1024) void k_sub(float* __restrict__ out) {
  int row = blockIdx.x;
  float* rb = out + (long)row * VOCAB;
  const unsigned int* src = reinterpret_cast<const unsigned int*>(rb);  // bf16 pairs
  int tid = threadIdx.x;
  unsigned int v[15];
  float se = 0.f;
  #pragma unroll
  for (int i = 0; i < 15; i++) {
    int p = tid + i * 1024;
    v[i] = (p < VOCAB / 2) ? src[p] : 0u;
  }
  #pragma unroll
  for (int i = 0; i < 15; i++) {
    int p = tid + i * 1024;
    if (p < VOCAB / 2) {
      unsigned int u = v[i];
      float lo = __uint_as_float((u & 0xffffu) << 16);
      float hi = __uint_as_float(u & 0xffff0000u);
      se += __expf(lo) + __expf(hi);
    }
  }
  #pragma unroll
  for (int off = 32; off; off >>= 1) se += __shfl_xor(se, off);
  __shared__ float red[16];
  int wid = tid >> 6;
  if ((tid & 63) == 0) red[wid] = se;
  __syncthreads();
  if (tid < 16) {
    float r = red[tid];
    #pragma unroll
    for (int off = 8; off; off >>= 1) r += __shfl_xor(r, off);
    if (tid == 0) red[0] = logf(r);
  }
  __syncthreads();
  float L = red[0];
  floatx2* dst = reinterpret_cast<floatx2*>(rb);
  #pragma unroll
  for (int i = 0; i < 15; i++) {
    int p = tid + i * 1024;
    if (p < VOCAB / 2) {
      unsigned int u = v[i];
      float lo = __uint_as_float((u & 0xffffu) << 16);
      float hi = __uint_as_float(u & 0xffff0000u);
      floatx2 o; o.x = lo - L; o.y = hi - L;
      dst[p] = o;
    }
  }
}

extern "C" void kernel_launch(void* const* d_in, const int* in_sizes, int n_in,
                              void* d_out, int out_size, void* d_ws, size_t ws_size,
                              hipStream_t stream) {
  const int* tok = (const int*)d_in[0];
  const int* typ = (const int*)d_in[1];
  const int* syn = (const int*)d_in[2];
  const int* hw  = (const int*)d_in[3];
  const float* tok_emb  = (const float*)d_in[4];
  const float* type_emb = (const float*)d_in[5];
  const float* pos_emb  = (const float*)d_in[6];
  const float* ln_g = (const float*)d_in[7];
  const float* ln_b = (const float*)d_in[8];
  const float* W    = (const float*)d_in[9];
  const float* a    = (const float*)d_in[10];
  const float* out_W = (const float*)d_in[11];
  const float* out_b = (const float*)d_in[12];
  float* out = (float*)d_out;
  char* ws = (char*)d_ws;
  // ws layout (bytes)
  unsigned short* xb = (unsigned short*)(ws + 0);          // 2048*768*2 = 3145728
  float* Wh  = (float*)(ws + 3145728);                     // 4*2048*128*4 = 4194304
  float* e1  = (float*)(ws + 7340032);                     // 32768
  float* e2  = (float*)(ws + 7372800);                     // 32768
  float* cm  = (float*)(ws + 7405568);                     // 32768
  float* cs  = (float*)(ws + 7438336);                     // 32768
  unsigned short* cat = (unsigned short*)(ws + 7471104);   // 2048*512*2 = 2097152
  unsigned short* Wt  = (unsigned short*)(ws + 9568256);   // 512*768*2 = 786432
  unsigned short* owb = (unsigned short*)(ws + 10354688);  // VPAD*512*2 = 31326208

  k_prep<<<4120, 256, 0, stream>>>(out_W, owb, W, Wt, tok, typ,
                                   tok_emb, type_emb, pos_emb, ln_g, ln_b, xb);
  k_wh<<<64, 256, 0, stream>>>(xb, Wt, Wh);
  k_ecol<<<32, 256, 0, stream>>>(tok, typ, syn, hw, Wh, a, e1, e2, cm, cs);
  k_att<<<256, 256, 0, stream>>>(tok, typ, syn, hw, e1, e2, cm, cs, Wh, cat);
  k_gemm<<<16 * NTILE, 256, 0, stream>>>(cat, owb, out_b, (unsigned short*)out);
  k_sub<<<2048, 1024, 0, stream>>>(out);
}

// Round 10
// 302.518 us; speedup vs baseline: 1.2016x; 1.0007x over previous
//
#include <hip/hip_runtime.h>
#include <hip/hip_bf16.h>

#define VOCAB 30522
#define VPAD 30592   // VOCAB padded to multiple of 128 (for branch-free B staging)
#define HIDDEN 768
#define NHEADS 4
#define NHID 128
#define ROWS 2048
#define KDIM 512
#define LN_EPS 1e-12f
#define ALPHA_LR 0.01f
#define NEGV -9.0e15f
#define NTILE 239   // ceil(30522/128)

typedef __attribute__((ext_vector_type(8))) short short8;
typedef __attribute__((ext_vector_type(4))) float floatx4;
typedef __attribute__((ext_vector_type(2))) float floatx2;
typedef __attribute__((ext_vector_type(4))) unsigned short ushort4v;
typedef __attribute__((ext_vector_type(8))) unsigned short ushort8v;

static __device__ __forceinline__ unsigned short f2bf(float f) {
  unsigned int u = __float_as_uint(f);
  unsigned int r = u + 0x7fffu + ((u >> 16) & 1u);
  return (unsigned short)(r >> 16);
}

// async global->LDS, 16B per lane (dest must be wave-linear: base + lane*16)
static __device__ __forceinline__ void gload16(const unsigned short* g, unsigned short* l) {
  __builtin_amdgcn_global_load_lds(
      (const __attribute__((address_space(1))) void*)g,
      (__attribute__((address_space(3))) void*)l, 16, 0, 0);
}

// ---------------- kernel A: fused preprocessing ----------------
// blocks [0,2048):       out_W fp32 -> bf16 (+ zero pad rows)
// blocks [2048,2072):    W (4,768,128) -> Wt (512,768) bf16 transposed (LDS transpose)
// blocks [2072,4120):    embeddings + LayerNorm -> xb bf16
__global__ __launch_bounds__(256) void k_prep(const float* __restrict__ out_W,
    unsigned short* __restrict__ owb,
    const float* __restrict__ W, unsigned short* __restrict__ Wt,
    const int* __restrict__ tok, const int* __restrict__ typ,
    const float* __restrict__ tok_emb, const float* __restrict__ type_emb, const float* __restrict__ pos_emb,
    const float* __restrict__ ln_g, const float* __restrict__ ln_b, unsigned short* __restrict__ xout) {
  __shared__ unsigned short T[128][136];   // transpose staging (34.8 KB)
  __shared__ float red[8];
  int bid = blockIdx.x;
  if (bid < 2048) {
    // ---- convert out_W ----
    int n4src = (VOCAB * KDIM) / 4, n4tot = (VPAD * KDIM) / 4;
    int i = bid * 256 + threadIdx.x;
    int stride = 2048 * 256;
    for (; i < n4tot; i += stride) {
      ushort4v o = {0, 0, 0, 0};
      if (i < n4src) {
        floatx4 v = reinterpret_cast<const floatx4*>(out_W)[i];
        o.x = f2bf(v.x); o.y = f2bf(v.y); o.z = f2bf(v.z); o.w = f2bf(v.w);
      }
      reinterpret_cast<ushort4v*>(owb)[i] = o;
    }
  } else if (bid < 2072) {
    // ---- transpose W -> Wt ----
    int b = bid - 2048;
    int h = b & 3, dc = b >> 2;          // dc in 0..5 (6 chunks of 128 d)
    int tid = threadIdx.x;
    const float* Wb = W + ((long)h * HIDDEN + dc * 128) * NHID;
    #pragma unroll
    for (int q = 0; q < 16; q++) {
      int idx = q * 256 + tid;           // 0..4095 over 128d x 32 f4
      int d = idx >> 5, f4 = idx & 31;
      floatx4 v = *reinterpret_cast<const floatx4*>(&Wb[(long)d * NHID + f4 * 4]);
      #pragma unroll
      for (int j = 0; j < 4; j++) T[f4 * 4 + j][d] = f2bf(v[j]);
    }
    __syncthreads();
    int f = tid >> 1, rh = tid & 1;
    unsigned short* dst = Wt + (long)(h * 128 + f) * HIDDEN + dc * 128 + rh * 64;
    #pragma unroll
    for (int i = 0; i < 8; i++)
      *reinterpret_cast<ushort8v*>(&dst[i * 8]) =
          *reinterpret_cast<const ushort8v*>(&T[f][rh * 64 + i * 8]);
  } else {
    // ---- embeddings + LN ----
    int row = bid - 2072;
    int n = row & 255;
    int t = tok[row], ty = typ[row];
    const float* te = tok_emb + (long)t * HIDDEN;
    const float* ye = type_emb + (long)ty * HIDDEN;
    const float* pe = pos_emb + (long)n * HIDDEN;
    float v[3]; float s = 0.f, ss = 0.f;
    #pragma unroll
    for (int q = 0; q < 3; q++) {
      int d = threadIdx.x + q * 256;
      float x = te[d] + ye[d] + pe[d];
      v[q] = x; s += x; ss += x * x;
    }
    for (int off = 32; off; off >>= 1) { s += __shfl_down(s, off); ss += __shfl_down(ss, off); }
    int wid = threadIdx.x >> 6;
    if ((threadIdx.x & 63) == 0) { red[wid] = s; red[4 + wid] = ss; }
    __syncthreads();
    if (threadIdx.x == 0) {
      float a = red[0] + red[1] + red[2] + red[3];
      float b2 = red[4] + red[5] + red[6] + red[7];
      float mu = a * (1.0f / 768.0f);
      float var = b2 * (1.0f / 768.0f) - mu * mu;
      red[0] = mu; red[1] = rsqrtf(var + LN_EPS);
    }
    __syncthreads();
    float mu = red[0], rstd = red[1];
    #pragma unroll
    for (int q = 0; q < 3; q++) {
      int d = threadIdx.x + q * 256;
      xout[(long)row * HIDDEN + d] = f2bf((v[q] - mu) * rstd * ln_g[d] + ln_b[d]);
    }
  }
}

// ---------------- kernel 2: Wh = x @ W (bf16 MFMA, counted-vmcnt pipeline) ----------------
// A = xb (2048 x 768 bf16), B = Wt (512 x 768 bf16, row=output col); Wh fp32 [h][row][f]
__global__ __launch_bounds__(256) void k_wh(const unsigned short* __restrict__ A,
    const unsigned short* __restrict__ Bw, float* __restrict__ Wh) {
  int mt = blockIdx.x & 15, nt = blockIdx.x >> 4;   // 16 x 4
  int m0 = mt * 128, n0 = nt * 128;
  __shared__ __align__(16) unsigned short Al[2][128 * 64];
  __shared__ __align__(16) unsigned short Bl[2][128 * 64];
  int tid = threadIdx.x;
  int l = tid & 63, wid = tid >> 6;
  int wr = wid >> 1, wc = wid & 1;
  int lrow = l & 15, lgrp = l >> 4;
  floatx4 acc[4][4];
  #pragma unroll
  for (int i = 0; i < 4; i++)
    #pragma unroll
    for (int j = 0; j < 4; j++) acc[i][j] = (floatx4){0.f, 0.f, 0.f, 0.f};
  const unsigned short* Ab = A + (long)m0 * HIDDEN;
  const unsigned short* Bb = Bw + (long)n0 * HIDDEN;

  auto STAGE = [&](int t, int bufi) {
    #pragma unroll
    for (int q = 0; q < 4; q++) {
      int chunk = q * 256 + tid;
      int row = chunk >> 3, kp = chunk & 7, swz = kp ^ (row & 7);
      long off = (long)row * HIDDEN + t * 64 + swz * 8;
      gload16(Ab + off, &Al[bufi][chunk * 8]);
      gload16(Bb + off, &Bl[bufi][chunk * 8]);
    }
  };

  STAGE(0, 0);
  STAGE(1, 1);
  asm volatile("s_waitcnt vmcnt(8)" ::: "memory");
  __builtin_amdgcn_sched_barrier(0);
  __builtin_amdgcn_s_barrier();

  #pragma unroll
  for (int kt = 0; kt < 12; kt++) {
    int cur = kt & 1;
    short8 af[2][4], bf[2][4];
    #pragma unroll
    for (int kk = 0; kk < 2; kk++) {
      int sA = (kk * 4 + lgrp) ^ (lrow & 7);
      #pragma unroll
      for (int mi = 0; mi < 4; mi++)
        af[kk][mi] = *reinterpret_cast<const short8*>(&Al[cur][(wr * 64 + mi * 16 + lrow) * 64 + sA * 8]);
      #pragma unroll
      for (int ni = 0; ni < 4; ni++)
        bf[kk][ni] = *reinterpret_cast<const short8*>(&Bl[cur][(wc * 64 + ni * 16 + lrow) * 64 + sA * 8]);
    }
    asm volatile("s_waitcnt lgkmcnt(0)" ::: "memory");
    __builtin_amdgcn_sched_barrier(0);
    __builtin_amdgcn_s_barrier();
    __builtin_amdgcn_sched_barrier(0);
    if (kt < 10) STAGE(kt + 2, cur);
    #pragma unroll
    for (int kk = 0; kk < 2; kk++)
      #pragma unroll
      for (int mi = 0; mi < 4; mi++)
        #pragma unroll
        for (int ni = 0; ni < 4; ni++)
          acc[mi][ni] = __builtin_amdgcn_mfma_f32_16x16x32_bf16(af[kk][mi], bf[kk][ni], acc[mi][ni], 0, 0, 0);
    if (kt < 10) {
      asm volatile("s_waitcnt vmcnt(8)" ::: "memory");
    } else if (kt == 10) {
      asm volatile("s_waitcnt vmcnt(0)" ::: "memory");
    }
    __builtin_amdgcn_sched_barrier(0);
    if (kt < 11) __builtin_amdgcn_s_barrier();
  }

  #pragma unroll
  for (int mi = 0; mi < 4; mi++) {
    #pragma unroll
    for (int reg = 0; reg < 4; reg++) {
      int row = m0 + wr * 64 + mi * 16 + lgrp * 4 + reg;
      #pragma unroll
      for (int ni = 0; ni < 4; ni++) {
        int c = n0 + wc * 64 + ni * 16 + lrow;
        int h = c >> 7, f = c & 127;
        Wh[((long)h * ROWS + row) * NHID + f] = acc[mi][ni][reg];
      }
    }
  }
}

__device__ __forceinline__ unsigned char mk_flags(int t, int hwv, int tokv) {
  unsigned char fl = 0;
  if (hwv) {
    if (t == 1) fl |= 1;
    if (t == 3) fl |= 2;
    if (t == 0 || t == 2 || t == 5) fl |= 4;
    if (t == 6 || t == 4 || t == 0) fl |= 8;
  }
  if (tokv != 0) fl |= 16;
  return fl;
}

// ---------------- kernel 3: fused e1/e2 + column softmax stats ----------------
__global__ __launch_bounds__(256) void k_ecol(const int* __restrict__ tok, const int* __restrict__ typ,
    const int* __restrict__ syn, const int* __restrict__ hw,
    const float* __restrict__ Wh, const float* __restrict__ a,
    float* __restrict__ e1, float* __restrict__ e2,
    float* __restrict__ colmax, float* __restrict__ colrs) {
  int h = blockIdx.x >> 3, b = blockIdx.x & 7;
  __shared__ float av[256];
  __shared__ float E1[256]; __shared__ int SY[256]; __shared__ unsigned char FL[256];
  int tid = threadIdx.x;
  int g = b * 256 + tid;
  av[tid] = a[h * 256 + tid];
  FL[tid] = mk_flags(typ[g], hw[g], tok[g]);
  SY[tid] = syn[g];
  __syncthreads();
  const float* wr = Wh + ((long)h * ROWS + g) * NHID;
  float s1 = 0.f, s2 = 0.f;
  #pragma unroll 8
  for (int f = 0; f < 128; f++) { float w = wr[f]; s1 += w * av[f]; s2 += w * av[128 + f]; }
  e1[h * ROWS + g] = s1; e2[h * ROWS + g] = s2;
  E1[tid] = s1;
  __syncthreads();
  float e2j = s2;
  int syj = SY[tid]; unsigned char flj = FL[tid];
  bool npj = flj & 16, d1j = flj & 4, d3j = flj & 8;
  float m = -INFINITY;
  for (int i = 0; i < 256; i++) {
    float e = E1[i] + e2j;
    e = e > 0.f ? e : ALPHA_LR * e;
    unsigned char fli = FL[i];
    bool vis = (SY[i] == syj) || ((fli & 1) && d1j) || ((fli & 2) && d3j);
    float v = (vis && npj) ? e : NEGV;
    m = fmaxf(m, v);
  }
  float s = 0.f;
  for (int i = 0; i < 256; i++) {
    float e = E1[i] + e2j;
    e = e > 0.f ? e : ALPHA_LR * e;
    unsigned char fli = FL[i];
    bool vis = (SY[i] == syj) || ((fli & 1) && d1j) || ((fli & 2) && d3j);
    float v = (vis && npj) ? e : NEGV;
    s += __expf(v - m);
  }
  int idx = (h * 8 + b) * 256 + tid;
  colmax[idx] = m;
  colrs[idx] = 1.0f / s;
}

// ---------------- kernel 4: hp = elu(att @ Wh) -> cat (bf16) ----------------
__global__ __launch_bounds__(256) void k_att(const int* __restrict__ tok, const int* __restrict__ typ,
    const int* __restrict__ syn, const int* __restrict__ hw,
    const float* __restrict__ e1, const float* __restrict__ e2,
    const float* __restrict__ colmax, const float* __restrict__ colrs,
    const float* __restrict__ Wh, unsigned short* __restrict__ cat) {
  int chunk = blockIdx.x & 7; int hb = blockIdx.x >> 3;
  int h = hb >> 3, b = hb & 7;
  __shared__ float E2[256], CM[256], CR[256];
  __shared__ int SY[256]; __shared__ unsigned char FL[256];
  __shared__ float WJ[64][128];
  int tid = threadIdx.x;
  {
    int g = b * 256 + tid;
    FL[tid] = mk_flags(typ[g], hw[g], tok[g]);
    E2[tid] = e2[h * ROWS + g];
    CM[tid] = colmax[hb * 256 + tid];
    CR[tid] = colrs[hb * 256 + tid];
    SY[tid] = syn[g];
  }
  __syncthreads();
  int i = chunk * 32 + (tid >> 3);
  int gi = b * 256 + i;
  float e1i = e1[h * ROWS + gi];
  unsigned char fli = FL[i];
  bool s1i = fli & 1, s3i = fli & 2;
  int syni = SY[i];
  int f0 = tid & 7;
  floatx4 acc4[4];
  #pragma unroll
  for (int k2 = 0; k2 < 4; k2++) acc4[k2] = (floatx4){0.f, 0.f, 0.f, 0.f};
  for (int j0 = 0; j0 < 256; j0 += 64) {
    #pragma unroll
    for (int q = 0; q < 8; q++) {
      int e = tid + q * 256;          // 0..2047
      int j = e >> 5, f4 = e & 31;
      *reinterpret_cast<floatx4*>(&WJ[j][f4 * 4]) =
          *reinterpret_cast<const floatx4*>(&Wh[((long)h * ROWS + b * 256 + j0 + j) * NHID + f4 * 4]);
    }
    __syncthreads();
    for (int j = 0; j < 64; j++) {
      int jj = j0 + j;
      unsigned char flj = FL[jj];
      bool vis = (syni == SY[jj]) || (s1i && (flj & 4)) || (s3i && (flj & 8));
      bool msk = vis && (flj & 16);
      float ev = e1i + E2[jj];
      ev = ev > 0.f ? ev : ALPHA_LR * ev;
      float v = msk ? ev : NEGV;
      float w = __expf(v - CM[jj]) * CR[jj];
      #pragma unroll
      for (int k2 = 0; k2 < 4; k2++) {
        floatx4 wv = *reinterpret_cast<const floatx4*>(&WJ[j][(f0 + 8 * k2) * 4]);
        acc4[k2] += wv * w;
      }
    }
    __syncthreads();
  }
  ushort4v* cr4 = reinterpret_cast<ushort4v*>(cat + (long)gi * KDIM + h * NHID);
  #pragma unroll
  for (int k2 = 0; k2 < 4; k2++) {
    ushort4v o4;
    #pragma unroll
    for (int e = 0; e < 4; e++) {
      float v = acc4[k2][e];
      v = v > 0.f ? v : __expf(v) - 1.f;
      o4[e] = f2bf(v);
    }
    cr4[f0 + 8 * k2] = o4;
  }
}

// ---------------- kernel 5: big GEMM (bf16 MFMA, 128x128, 512 threads / 8 waves) ----------------
// 2 blocks/CU x 8 waves = 4 waves/SIMD. Same counted-vmcnt skeleton; per-wave output 64x32.
// writes bf16 elu'd logits into the first half of each output row's fp32 slot
__global__ __launch_bounds__(512) void k_gemm(const unsigned short* __restrict__ A,
    const unsigned short* __restrict__ Bw, const float* __restrict__ bias,
    unsigned short* __restrict__ otmp) {
  // bijective XCD swizzle: 3824 blocks, 3824 % 8 == 0
  int bid = blockIdx.x;
  bid = (bid & 7) * ((16 * NTILE) >> 3) + (bid >> 3);
  int mt = bid & 15, nt = bid >> 4;
  int m0 = mt * 128, n0 = nt * 128;
  // LDS: staging buffers (64 KB) overlaid with C epilogue tile [128][136] (34.8 KB)
  __shared__ __align__(16) char smem[65536];
  unsigned short (*Al)[128 * 64] = reinterpret_cast<unsigned short (*)[128 * 64]>(smem);
  unsigned short (*Bl)[128 * 64] = reinterpret_cast<unsigned short (*)[128 * 64]>(smem + 32768);
  unsigned short* Cl = reinterpret_cast<unsigned short*>(smem);
  int tid = threadIdx.x;
  int l = tid & 63, wid = tid >> 6;          // 8 waves
  int wr = wid >> 2, wc = wid & 3;           // 2 x 4 -> per-wave 64 rows x 32 cols
  int lrow = l & 15, lgrp = l >> 4;
  floatx4 acc[4][2];
  #pragma unroll
  for (int i = 0; i < 4; i++)
    #pragma unroll
    for (int j = 0; j < 2; j++) acc[i][j] = (floatx4){0.f, 0.f, 0.f, 0.f};
  const unsigned short* Ab = A + (long)m0 * KDIM;
  const unsigned short* Bb = Bw + (long)n0 * KDIM;

  // stage tile t: A 128x64 (2 loads/thread), B 128x64 (2 loads/thread) -> 4 VMEM inst/thread
  auto STAGE = [&](int t, int bufi) {
    #pragma unroll
    for (int q = 0; q < 2; q++) {
      int chunk = q * 512 + tid;             // 0..1023
      int row = chunk >> 3, kp = chunk & 7, swz = kp ^ (row & 7);
      long off = (long)row * KDIM + t * 64 + swz * 8;
      gload16(Ab + off, &Al[bufi][chunk * 8]);
      gload16(Bb + off, &Bl[bufi][chunk * 8]);
    }
  };

  STAGE(0, 0);
  STAGE(1, 1);
  asm volatile("s_waitcnt vmcnt(4)" ::: "memory");   // tile 0 landed; tile 1 (4 loads) in flight
  __builtin_amdgcn_sched_barrier(0);
  __builtin_amdgcn_s_barrier();

  #pragma unroll
  for (int kt = 0; kt < 8; kt++) {
    int cur = kt & 1;
    short8 af[2][4], bf[2][2];
    #pragma unroll
    for (int kk = 0; kk < 2; kk++) {
      int sA = (kk * 4 + lgrp) ^ (lrow & 7);
      #pragma unroll
      for (int mi = 0; mi < 4; mi++)
        af[kk][mi] = *reinterpret_cast<const short8*>(&Al[cur][(wr * 64 + mi * 16 + lrow) * 64 + sA * 8]);
      #pragma unroll
      for (int ni = 0; ni < 2; ni++)
        bf[kk][ni] = *reinterpret_cast<const short8*>(&Bl[cur][(wc * 32 + ni * 16 + lrow) * 64 + sA * 8]);
    }
    asm volatile("s_waitcnt lgkmcnt(0)" ::: "memory");  // my reads of buf[cur] complete
    __builtin_amdgcn_sched_barrier(0);
    __builtin_amdgcn_s_barrier();                       // ALL waves done reading buf[cur]
    __builtin_amdgcn_sched_barrier(0);
    if (kt < 6) STAGE(kt + 2, cur);                     // overwrite buf[cur] with tile kt+2
    #pragma unroll
    for (int kk = 0; kk < 2; kk++)
      #pragma unroll
      for (int mi = 0; mi < 4; mi++)
        #pragma unroll
        for (int ni = 0; ni < 2; ni++)
          acc[mi][ni] = __builtin_amdgcn_mfma_f32_16x16x32_bf16(af[kk][mi], bf[kk][ni], acc[mi][ni], 0, 0, 0);
    if (kt < 6) {
      asm volatile("s_waitcnt vmcnt(4)" ::: "memory");  // tile kt+1 landed; kt+2 (4 loads) in flight
    } else if (kt == 6) {
      asm volatile("s_waitcnt vmcnt(0)" ::: "memory");  // tail: tile 7 landed
    }
    __builtin_amdgcn_sched_barrier(0);
    if (kt < 7) __builtin_amdgcn_s_barrier();
  }
  // NOTE: after the kt=7 barrier (post-lgkmcnt), no wave reads Al/Bl again ->
  // safe to overwrite the stage LDS with the C tile.

  // epilogue phase 1: bias + elu -> bf16 into Cl[128][136]
  float bcol[2];
  #pragma unroll
  for (int ni = 0; ni < 2; ni++) {
    int c = n0 + wc * 32 + ni * 16 + lrow;
    bcol[ni] = (c < VOCAB) ? bias[c] : 0.f;   // pad cols: B rows are zero -> z=0 -> elu=0
  }
  #pragma unroll
  for (int mi = 0; mi < 4; mi++)
    #pragma unroll
    for (int ni = 0; ni < 2; ni++)
      #pragma unroll
      for (int reg = 0; reg < 4; reg++) {
        int r = wr * 64 + mi * 16 + lgrp * 4 + reg;
        int c = wc * 32 + ni * 16 + lrow;
        float z = acc[mi][ni][reg] + bcol[ni];
        float o = z > 0.f ? z : __expf(z) - 1.f;
        Cl[r * 136 + c] = f2bf(o);
      }
  __syncthreads();
  // epilogue phase 2: coalesced stores — 16 threads/row x 16B, 32 rows/pass x 4 passes
  #pragma unroll
  for (int it = 0; it < 4; it++) {
    int r = it * 32 + (tid >> 4);
    int c = (tid & 15) * 8;
    int gc = n0 + c;
    ushort8v v = *reinterpret_cast<const ushort8v*>(&Cl[r * 136 + c]);
    unsigned short* orow = otmp + (long)(m0 + r) * 2 * VOCAB;
    if (gc + 8 <= VOCAB) {
      *reinterpret_cast<ushort8v*>(orow + gc) = v;
    } else {
      #pragma unroll
      for (int e = 0; e < 8; e++)
        if (gc + e < VOCAB) orow[gc + e] = v[e];
    }
  }
}

// ---------------- kernel 6: in-place bf16 -> (fp32 - lse) with in-block lse ----------------
__global__ __launch_bounds__(1024) void k_sub(float* __restrict__ out) {
  int row = blockIdx.x;
  float* rb = out + (long)row * VOCAB;
  const unsigned int* src = reinterpret_cast<const unsigned int*>(rb);  // bf16 pairs
  int tid = threadIdx.x;
  unsigned int v[15];
  float se = 0.f;
  #pragma unroll
  for (int i = 0; i < 15; i++) {
    int p = tid + i * 1024;
    v[i] = (p < VOCAB / 2) ? src[p] : 0u;
  }
  #pragma unroll
  for (int i = 0; i < 15; i++) {
    int p = tid + i * 1024;
    if (p < VOCAB / 2) {
      unsigned int u = v[i];
      float lo = __uint_as_float((u & 0xffffu) << 16);
      float hi = __uint_as_float(u & 0xffff0000u);
      se += __expf(lo) + __expf(hi);
    }
  }
  #pragma unroll
  for (int off = 32; off; off >>= 1) se += __shfl_xor(se, off);
  __shared__ float red[16];
  int wid = tid >> 6;
  if ((tid & 63) == 0) red[wid] = se;
  __syncthreads();
  if (tid < 16) {
    float r = red[tid];
    #pragma unroll
    for (int off = 8; off; off >>= 1) r += __shfl_xor(r, off);
    if (tid == 0) red[0] = logf(r);
  }
  __syncthreads();
  float L = red[0];
  floatx2* dst = reinterpret_cast<floatx2*>(rb);
  #pragma unroll
  for (int i = 0; i < 15; i++) {
    int p = tid + i * 1024;
    if (p < VOCAB / 2) {
      unsigned int u = v[i];
      float lo = __uint_as_float((u & 0xffffu) << 16);
      float hi = __uint_as_float(u & 0xffff0000u);
      floatx2 o; o.x = lo - L; o.y = hi - L;
      dst[p] = o;
    }
  }
}

extern "C" void kernel_launch(void* const* d_in, const int* in_sizes, int n_in,
                              void* d_out, int out_size, void* d_ws, size_t ws_size,
                              hipStream_t stream) {
  const int* tok = (const int*)d_in[0];
  const int* typ = (const int*)d_in[1];
  const int* syn = (const int*)d_in[2];
  const int* hw  = (const int*)d_in[3];
  const float* tok_emb  = (const float*)d_in[4];
  const float* type_emb = (const float*)d_in[5];
  const float* pos_emb  = (const float*)d_in[6];
  const float* ln_g = (const float*)d_in[7];
  const float* ln_b = (const float*)d_in[8];
  const float* W    = (const float*)d_in[9];
  const float* a    = (const float*)d_in[10];
  const float* out_W = (const float*)d_in[11];
  const float* out_b = (const float*)d_in[12];
  float* out = (float*)d_out;
  char* ws = (char*)d_ws;
  // ws layout (bytes)
  unsigned short* xb = (unsigned short*)(ws + 0);          // 2048*768*2 = 3145728
  float* Wh  = (float*)(ws + 3145728);                     // 4*2048*128*4 = 4194304
  float* e1  = (float*)(ws + 7340032);                     // 32768
  float* e2  = (float*)(ws + 7372800);                     // 32768
  float* cm  = (float*)(ws + 7405568);                     // 32768
  float* cs  = (float*)(ws + 7438336);                     // 32768
  unsigned short* cat = (unsigned short*)(ws + 7471104);   // 2048*512*2 = 2097152
  unsigned short* Wt  = (unsigned short*)(ws + 9568256);   // 512*768*2 = 786432
  unsigned short* owb = (unsigned short*)(ws + 10354688);  // VPAD*512*2 = 31326208

  k_prep<<<4120, 256, 0, stream>>>(out_W, owb, W, Wt, tok, typ,
                                   tok_emb, type_emb, pos_emb, ln_g, ln_b, xb);
  k_wh<<<64, 256, 0, stream>>>(xb, Wt, Wh);
  k_ecol<<<32, 256, 0, stream>>>(tok, typ, syn, hw, Wh, a, e1, e2, cm, cs);
  k_att<<<256, 256, 0, stream>>>(tok, typ, syn, hw, e1, e2, cm, cs, Wh, cat);
  k_gemm<<<16 * NTILE, 512, 0, stream>>>(cat, owb, out_b, (unsigned short*)out);
  k_sub<<<2048, 1024, 0, stream>>>(out);
}

// Round 14
// 301.760 us; speedup vs baseline: 1.2046x; 1.0025x over previous
//
#include <hip/hip_runtime.h>
#include <hip/hip_bf16.h>

#define VOCAB 30522
#define VPAD 30720
#define HIDDEN 768
#define NHEADS 4
#define NHID 128
#define ROWS 2048
#define KDIM 512
#define LN_EPS 1e-12f
#define ALPHA_LR 0.01f
#define NEGV -9.0e15f
#define NT256 120

typedef __attribute__((ext_vector_type(8))) short short8;
typedef __attribute__((ext_vector_type(4))) float floatx4;
typedef __attribute__((ext_vector_type(2))) float floatx2;
typedef __attribute__((ext_vector_type(4))) unsigned short ushort4v;
typedef __attribute__((ext_vector_type(8))) unsigned short ushort8v;

static __device__ __forceinline__ unsigned short f2bf(float f) {
  unsigned int u = __float_as_uint(f);
  unsigned int r = u + 0x7fffu + ((u >> 16) & 1u);
  return (unsigned short)(r >> 16);
}

static __device__ __forceinline__ void gload16(const unsigned short* g, unsigned short* l) {
  __builtin_amdgcn_global_load_lds(
      (const __attribute__((address_space(1))) void*)g,
      (__attribute__((address_space(3))) void*)l, 16, 0, 0);
}

// ---------------- kernel A: fused preprocessing ----------------
__global__ __launch_bounds__(256) void k_prep(const float* __restrict__ out_W,
    unsigned short* __restrict__ owb,
    const float* __restrict__ W, unsigned short* __restrict__ Wt,
    const int* __restrict__ tok, const int* __restrict__ typ,
    const float* __restrict__ tok_emb, const float* __restrict__ type_emb, const float* __restrict__ pos_emb,
    const float* __restrict__ ln_g, const float* __restrict__ ln_b, unsigned short* __restrict__ xout) {
  __shared__ unsigned short T[128][136];
  __shared__ float red[8];
  int bid = blockIdx.x;
  if (bid < 2048) {
    int n4src = (VOCAB * KDIM) / 4, n4tot = (VPAD * KDIM) / 4;
    int i = bid * 256 + threadIdx.x;
    int stride = 2048 * 256;
    for (; i < n4tot; i += stride) {
      ushort4v o = {0, 0, 0, 0};
      if (i < n4src) {
        floatx4 v = reinterpret_cast<const floatx4*>(out_W)[i];
        o.x = f2bf(v.x); o.y = f2bf(v.y); o.z = f2bf(v.z); o.w = f2bf(v.w);
      }
      reinterpret_cast<ushort4v*>(owb)[i] = o;
    }
  } else if (bid < 2072) {
    int b = bid - 2048;
    int h = b & 3, dc = b >> 2;
    int tid = threadIdx.x;
    const float* Wb = W + ((long)h * HIDDEN + dc * 128) * NHID;
    #pragma unroll
    for (int q = 0; q < 16; q++) {
      int idx = q * 256 + tid;
      int d = idx >> 5, f4 = idx & 31;
      floatx4 v = *reinterpret_cast<const floatx4*>(&Wb[(long)d * NHID + f4 * 4]);
      #pragma unroll
      for (int j = 0; j < 4; j++) T[f4 * 4 + j][d] = f2bf(v[j]);
    }
    __syncthreads();
    int f = tid >> 1, rh = tid & 1;
    unsigned short* dst = Wt + (long)(h * 128 + f) * HIDDEN + dc * 128 + rh * 64;
    #pragma unroll
    for (int i = 0; i < 8; i++)
      *reinterpret_cast<ushort8v*>(&dst[i * 8]) =
          *reinterpret_cast<const ushort8v*>(&T[f][rh * 64 + i * 8]);
  } else {
    int row = bid - 2072;
    int n = row & 255;
    int t = tok[row], ty = typ[row];
    const float* te = tok_emb + (long)t * HIDDEN;
    const float* ye = type_emb + (long)ty * HIDDEN;
    const float* pe = pos_emb + (long)n * HIDDEN;
    float v[3]; float s = 0.f, ss = 0.f;
    #pragma unroll
    for (int q = 0; q < 3; q++) {
      int d = threadIdx.x + q * 256;
      float x = te[d] + ye[d] + pe[d];
      v[q] = x; s += x; ss += x * x;
    }
    for (int off = 32; off; off >>= 1) { s += __shfl_down(s, off); ss += __shfl_down(ss, off); }
    int wid = threadIdx.x >> 6;
    if ((threadIdx.x & 63) == 0) { red[wid] = s; red[4 + wid] = ss; }
    __syncthreads();
    if (threadIdx.x == 0) {
      float a = red[0] + red[1] + red[2] + red[3];
      float b2 = red[4] + red[5] + red[6] + red[7];
      float mu = a * (1.0f / 768.0f);
      float var = b2 * (1.0f / 768.0f) - mu * mu;
      red[0] = mu; red[1] = rsqrtf(var + LN_EPS);
    }
    __syncthreads();
    float mu = red[0], rstd = red[1];
    #pragma unroll
    for (int q = 0; q < 3; q++) {
      int d = threadIdx.x + q * 256;
      xout[(long)row * HIDDEN + d] = f2bf((v[q] - mu) * rstd * ln_g[d] + ln_b[d]);
    }
  }
}

// ---------------- kernel 2: Wh = x @ W (bf16 MFMA) ----------------
__global__ __launch_bounds__(256) void k_wh(const unsigned short* __restrict__ A,
    const unsigned short* __restrict__ Bw, float* __restrict__ Wh) {
  int mt = blockIdx.x & 15, nt = blockIdx.x >> 4;
  int m0 = mt * 128, n0 = nt * 128;
  __shared__ __align__(16) unsigned short Al[2][128 * 64];
  __shared__ __align__(16) unsigned short Bl[2][128 * 64];
  int tid = threadIdx.x;
  int l = tid & 63, wid = tid >> 6;
  int wr = wid >> 1, wc = wid & 1;
  int lrow = l & 15, lgrp = l >> 4;
  floatx4 acc[4][4];
  #pragma unroll
  for (int i = 0; i < 4; i++)
    #pragma unroll
    for (int j = 0; j < 4; j++) acc[i][j] = (floatx4){0.f, 0.f, 0.f, 0.f};
  const unsigned short* Ab = A + (long)m0 * HIDDEN;
  const unsigned short* Bb = Bw + (long)n0 * HIDDEN;

  auto STAGE = [&](int t, int bufi) {
    #pragma unroll
    for (int q = 0; q < 4; q++) {
      int chunk = q * 256 + tid;
      int row = chunk >> 3, kp = chunk & 7, swz = kp ^ (row & 7);
      long off = (long)row * HIDDEN + t * 64 + swz * 8;
      gload16(Ab + off, &Al[bufi][chunk * 8]);
      gload16(Bb + off, &Bl[bufi][chunk * 8]);
    }
  };

  STAGE(0, 0);
  STAGE(1, 1);
  asm volatile("s_waitcnt vmcnt(8)" ::: "memory");
  __builtin_amdgcn_sched_barrier(0);
  __builtin_amdgcn_s_barrier();

  #pragma unroll
  for (int kt = 0; kt < 12; kt++) {
    int cur = kt & 1;
    short8 af[2][4], bf[2][4];
    #pragma unroll
    for (int kk = 0; kk < 2; kk++) {
      int sA = (kk * 4 + lgrp) ^ (lrow & 7);
      #pragma unroll
      for (int mi = 0; mi < 4; mi++)
        af[kk][mi] = *reinterpret_cast<const short8*>(&Al[cur][(wr * 64 + mi * 16 + lrow) * 64 + sA * 8]);
      #pragma unroll
      for (int ni = 0; ni < 4; ni++)
        bf[kk][ni] = *reinterpret_cast<const short8*>(&Bl[cur][(wc * 64 + ni * 16 + lrow) * 64 + sA * 8]);
    }
    asm volatile("s_waitcnt lgkmcnt(0)" ::: "memory");
    __builtin_amdgcn_sched_barrier(0);
    __builtin_amdgcn_s_barrier();
    __builtin_amdgcn_sched_barrier(0);
    if (kt < 10) STAGE(kt + 2, cur);
    #pragma unroll
    for (int kk = 0; kk < 2; kk++)
      #pragma unroll
      for (int mi = 0; mi < 4; mi++)
        #pragma unroll
        for (int ni = 0; ni < 4; ni++)
          acc[mi][ni] = __builtin_amdgcn_mfma_f32_16x16x32_bf16(af[kk][mi], bf[kk][ni], acc[mi][ni], 0, 0, 0);
    if (kt < 10) {
      asm volatile("s_waitcnt vmcnt(8)" ::: "memory");
    } else if (kt == 10) {
      asm volatile("s_waitcnt vmcnt(0)" ::: "memory");
    }
    __builtin_amdgcn_sched_barrier(0);
    if (kt < 11) __builtin_amdgcn_s_barrier();
  }

  #pragma unroll
  for (int mi = 0; mi < 4; mi++) {
    #pragma unroll
    for (int reg = 0; reg < 4; reg++) {
      int row = m0 + wr * 64 + mi * 16 + lgrp * 4 + reg;
      #pragma unroll
      for (int ni = 0; ni < 4; ni++) {
        int c = n0 + wc * 64 + ni * 16 + lrow;
        int h = c >> 7, f = c & 127;
        Wh[((long)h * ROWS + row) * NHID + f] = acc[mi][ni][reg];
      }
    }
  }
}

__device__ __forceinline__ unsigned char mk_flags(int t, int hwv, int tokv) {
  unsigned char fl = 0;
  if (hwv) {
    if (t == 1) fl |= 1;
    if (t == 3) fl |= 2;
    if (t == 0 || t == 2 || t == 5) fl |= 4;
    if (t == 6 || t == 4 || t == 0) fl |= 8;
  }
  if (tokv != 0) fl |= 16;
  return fl;
}

// ---------------- kernel 3: fused e1/e2 + column softmax stats ----------------
__global__ __launch_bounds__(256) void k_ecol(const int* __restrict__ tok, const int* __restrict__ typ,
    const int* __restrict__ syn, const int* __restrict__ hw,
    const float* __restrict__ Wh, const float* __restrict__ a,
    float* __restrict__ e1, float* __restrict__ e2,
    float* __restrict__ colmax, float* __restrict__ colrs) {
  int h = blockIdx.x >> 3, b = blockIdx.x & 7;
  __shared__ float av[256];
  __shared__ float E1[256]; __shared__ int SY[256]; __shared__ unsigned char FL[256];
  int tid = threadIdx.x;
  int g = b * 256 + tid;
  av[tid] = a[h * 256 + tid];
  FL[tid] = mk_flags(typ[g], hw[g], tok[g]);
  SY[tid] = syn[g];
  __syncthreads();
  const float* wr = Wh + ((long)h * ROWS + g) * NHID;
  float s1 = 0.f, s2 = 0.f;
  #pragma unroll 8
  for (int f = 0; f < 128; f++) { float w = wr[f]; s1 += w * av[f]; s2 += w * av[128 + f]; }
  e1[h * ROWS + g] = s1; e2[h * ROWS + g] = s2;
  E1[tid] = s1;
  __syncthreads();
  float e2j = s2;
  int syj = SY[tid]; unsigned char flj = FL[tid];
  bool npj = flj & 16, d1j = flj & 4, d3j = flj & 8;
  float m = -INFINITY;
  for (int i = 0; i < 256; i++) {
    float e = E1[i] + e2j;
    e = e > 0.f ? e : ALPHA_LR * e;
    unsigned char fli = FL[i];
    bool vis = (SY[i] == syj) || ((fli & 1) && d1j) || ((fli & 2) && d3j);
    float v = (vis && npj) ? e : NEGV;
    m = fmaxf(m, v);
  }
  float s = 0.f;
  for (int i = 0; i < 256; i++) {
    float e = E1[i] + e2j;
    e = e > 0.f ? e : ALPHA_LR * e;
    unsigned char fli = FL[i];
    bool vis = (SY[i] == syj) || ((fli & 1) && d1j) || ((fli & 2) && d3j);
    float v = (vis && npj) ? e : NEGV;
    s += __expf(v - m);
  }
  int idx = (h * 8 + b) * 256 + tid;
  colmax[idx] = m;
  colrs[idx] = 1.0f / s;
}

// ---------------- kernel 4: hp = elu(att @ Wh) -> cat (bf16) ----------------
__global__ __launch_bounds__(256) void k_att(const int* __restrict__ tok, const int* __restrict__ typ,
    const int* __restrict__ syn, const int* __restrict__ hw,
    const float* __restrict__ e1, const float* __restrict__ e2,
    const float* __restrict__ colmax, const float* __restrict__ colrs,
    const float* __restrict__ Wh, unsigned short* __restrict__ cat) {
  int chunk = blockIdx.x & 7; int hb = blockIdx.x >> 3;
  int h = hb >> 3, b = hb & 7;
  __shared__ float E2[256], CM[256], CR[256];
  __shared__ int SY[256]; __shared__ unsigned char FL[256];
  __shared__ float WJ[64][128];
  int tid = threadIdx.x;
  {
    int g = b * 256 + tid;
    FL[tid] = mk_flags(typ[g], hw[g], tok[g]);
    E2[tid] = e2[h * ROWS + g];
    CM[tid] = colmax[hb * 256 + tid];
    CR[tid] = colrs[hb * 256 + tid];
    SY[tid] = syn[g];
  }
  __syncthreads();
  int i = chunk * 32 + (tid >> 3);
  int gi = b * 256 + i;
  float e1i = e1[h * ROWS + gi];
  unsigned char fli = FL[i];
  bool s1i = fli & 1, s3i = fli & 2;
  int syni = SY[i];
  int f0 = tid & 7;
  floatx4 acc4[4];
  #pragma unroll
  for (int k2 = 0; k2 < 4; k2++) acc4[k2] = (floatx4){0.f, 0.f, 0.f, 0.f};
  for (int j0 = 0; j0 < 256; j0 += 64) {
    #pragma unroll
    for (int q = 0; q < 8; q++) {
      int e = tid + q * 256;
      int j = e >> 5, f4 = e & 31;
      *reinterpret_cast<floatx4*>(&WJ[j][f4 * 4]) =
          *reinterpret_cast<const floatx4*>(&Wh[((long)h * ROWS + b * 256 + j0 + j) * NHID + f4 * 4]);
    }
    __syncthreads();
    for (int j = 0; j < 64; j++) {
      int jj = j0 + j;
      unsigned char flj = FL[jj];
      bool vis = (syni == SY[jj]) || (s1i && (flj & 4)) || (s3i && (flj & 8));
      bool msk = vis && (flj & 16);
      float ev = e1i + E2[jj];
      ev = ev > 0.f ? ev : ALPHA_LR * ev;
      float v = msk ? ev : NEGV;
      float w = __expf(v - CM[jj]) * CR[jj];
      #pragma unroll
      for (int k2 = 0; k2 < 4; k2++) {
        floatx4 wv = *reinterpret_cast<const floatx4*>(&WJ[j][(f0 + 8 * k2) * 4]);
        acc4[k2] += wv * w;
      }
    }
    __syncthreads();
  }
  ushort4v* cr4 = reinterpret_cast<ushort4v*>(cat + (long)gi * KDIM + h * NHID);
  #pragma unroll
  for (int k2 = 0; k2 < 4; k2++) {
    ushort4v o4;
    #pragma unroll
    for (int e = 0; e < 4; e++) {
      float v = acc4[k2][e];
      v = v > 0.f ? v : __expf(v) - 1.f;
      o4[e] = f2bf(v);
    }
    cr4[f0 + 8 * k2] = o4;
  }
}

// ---------------- kernel 5: big GEMM (bf16 MFMA, 256x256 tile, 8 waves, quadrant-phased) ----------------
__global__ __launch_bounds__(512, 2) void k_gemm(const unsigned short* __restrict__ A,
    const unsigned short* __restrict__ Bw, const float* __restrict__ bias,
    unsigned short* __restrict__ otmp) {
  int bid = blockIdx.x;
  int lin = (bid & 7) * NT256 + (bid >> 3);
  int mt = lin & 7, nt = lin >> 3;
  int m0 = mt * 256, n0 = nt * 256;
  __shared__ __align__(16) char smem[131072];
  unsigned short (*Al)[256 * 64] = reinterpret_cast<unsigned short (*)[256 * 64]>(smem);
  unsigned short (*Bl)[256 * 64] = reinterpret_cast<unsigned short (*)[256 * 64]>(smem + 65536);
  unsigned short* Cl = reinterpret_cast<unsigned short*>(smem);
  int tid = threadIdx.x;
  int l = tid & 63, wid = tid >> 6;
  int wr = wid >> 2, wc = wid & 3;
  int lrow = l & 15, lgrp = l >> 4;
  floatx4 acc[8][4];
  #pragma unroll
  for (int i = 0; i < 8; i++)
    #pragma unroll
    for (int j = 0; j < 4; j++) acc[i][j] = (floatx4){0.f, 0.f, 0.f, 0.f};
  const unsigned short* Ab = A + (long)m0 * KDIM;
  const unsigned short* Bb = Bw + (long)n0 * KDIM;

  auto STAGE = [&](int t, int bufi) {
    #pragma unroll
    for (int q = 0; q < 4; q++) {
      int chunk = q * 512 + tid;
      int row = chunk >> 3, kp = chunk & 7, swz = kp ^ (row & 7);
      long off = (long)row * KDIM + t * 64 + swz * 8;
      gload16(Ab + off, &Al[bufi][chunk * 8]);
      gload16(Bb + off, &Bl[bufi][chunk * 8]);
    }
  };

  STAGE(0, 0);
  STAGE(1, 1);
  asm volatile("s_waitcnt vmcnt(8)" ::: "memory");
  __builtin_amdgcn_sched_barrier(0);
  __builtin_amdgcn_s_barrier();

  #pragma unroll
  for (int kt = 0; kt < 8; kt++) {
    int cur = kt & 1;
    short8 afr[8];
    short8 bfr[4];
    // phase 0: (mh=0, nh=0)
    #pragma unroll
    for (int mi = 0; mi < 4; mi++)
      #pragma unroll
      for (int ks = 0; ks < 2; ks++)
        afr[mi * 2 + ks] = *reinterpret_cast<const short8*>(
            &Al[cur][(wr * 128 + mi * 16 + lrow) * 64 + (((ks * 4 + lgrp) ^ (lrow & 7)) * 8)]);
    #pragma unroll
    for (int ni = 0; ni < 2; ni++)
      #pragma unroll
      for (int ks = 0; ks < 2; ks++)
        bfr[ni * 2 + ks] = *reinterpret_cast<const short8*>(
            &Bl[cur][(wc * 64 + ni * 16 + lrow) * 64 + (((ks * 4 + lgrp) ^ (lrow & 7)) * 8)]);
    #pragma unroll
    for (int ks = 0; ks < 2; ks++)
      #pragma unroll
      for (int mi = 0; mi < 4; mi++)
        #pragma unroll
        for (int ni = 0; ni < 2; ni++)
          acc[mi][ni] = __builtin_amdgcn_mfma_f32_16x16x32_bf16(afr[mi * 2 + ks], bfr[ni * 2 + ks], acc[mi][ni], 0, 0, 0);
    __builtin_amdgcn_sched_barrier(0);
    // phase 1: (mh=0, nh=1) - new B, reuse A
    #pragma unroll
    for (int ni = 0; ni < 2; ni++)
      #pragma unroll
      for (int ks = 0; ks < 2; ks++)
        bfr[ni * 2 + ks] = *reinterpret_cast<const short8*>(
            &Bl[cur][(wc * 64 + (2 + ni) * 16 + lrow) * 64 + (((ks * 4 + lgrp) ^ (lrow & 7)) * 8)]);
    #pragma unroll
    for (int ks = 0; ks < 2; ks++)
      #pragma unroll
      for (int mi = 0; mi < 4; mi++)
        #pragma unroll
        for (int ni = 0; ni < 2; ni++)
          acc[mi][2 + ni] = __builtin_amdgcn_mfma_f32_16x16x32_bf16(afr[mi * 2 + ks], bfr[ni * 2 + ks], acc[mi][2 + ni], 0, 0, 0);
    __builtin_amdgcn_sched_barrier(0);
    // phase 2: (mh=1, nh=1) - new A, reuse B
    #pragma unroll
    for (int mi = 0; mi < 4; mi++)
      #pragma unroll
      for (int ks = 0; ks < 2; ks++)
        afr[mi * 2 + ks] = *reinterpret_cast<const short8*>(
            &Al[cur][(wr * 128 + (4 + mi) * 16 + lrow) * 64 + (((ks * 4 + lgrp) ^ (lrow & 7)) * 8)]);
    #pragma unroll
    for (int ks = 0; ks < 2; ks++)
      #pragma unroll
      for (int mi = 0; mi < 4; mi++)
        #pragma unroll
        for (int ni = 0; ni < 2; ni++)
          acc[4 + mi][2 + ni] = __builtin_amdgcn_mfma_f32_16x16x32_bf16(afr[mi * 2 + ks], bfr[ni * 2 + ks], acc[4 + mi][2 + ni], 0, 0, 0);
    __builtin_amdgcn_sched_barrier(0);
    // phase 3: (mh=1, nh=0) - re-read B nh0; last reads of buf[cur]
    #pragma unroll
    for (int ni = 0; ni < 2; ni++)
      #pragma unroll
      for (int ks = 0; ks < 2; ks++)
        bfr[ni * 2 + ks] = *reinterpret_cast<const short8*>(
            &Bl[cur][(wc * 64 + ni * 16 + lrow) * 64 + (((ks * 4 + lgrp) ^ (lrow & 7)) * 8)]);
    asm volatile("s_waitcnt lgkmcnt(0)" ::: "memory");
    __builtin_amdgcn_sched_barrier(0);
    __builtin_amdgcn_s_barrier();
    __builtin_amdgcn_sched_barrier(0);
    if (kt < 6) STAGE(kt + 2, cur);
    #pragma unroll
    for (int ks = 0; ks < 2; ks++)
      #pragma unroll
      for (int mi = 0; mi < 4; mi++)
        #pragma unroll
        for (int ni = 0; ni < 2; ni++)
          acc[4 + mi][ni] = __builtin_amdgcn_mfma_f32_16x16x32_bf16(afr[mi * 2 + ks], bfr[ni * 2 + ks], acc[4 + mi][ni], 0, 0, 0);
    if (kt < 6) {
      asm volatile("s_waitcnt vmcnt(8)" ::: "memory");
    } else if (kt == 6) {
      asm volatile("s_waitcnt vmcnt(0)" ::: "memory");
    }
    __builtin_amdgcn_sched_barrier(0);
    if (kt < 7) __builtin_amdgcn_s_barrier();
  }
  // epilogue phase 1: bias + elu -> bf16 into Cl[256][256]
  float bcol[4];
  #pragma unroll
  for (int ni = 0; ni < 4; ni++) {
    int c = n0 + wc * 64 + ni * 16 + lrow;
    bcol[ni] = (c < VOCAB) ? bias[c] : 0.f;
  }
  #pragma unroll
  for (int mi = 0; mi < 8; mi++)
    #pragma unroll
    for (int ni = 0; ni < 4; ni++)
      #pragma unroll
      for (int reg = 0; reg < 4; reg++) {
        int r = wr * 128 + mi * 16 + lgrp * 4 + reg;
        int c = wc * 64 + ni * 16 + lrow;
        float z = acc[mi][ni][reg] + bcol[ni];
        float o = z > 0.f ? z : __expf(z) - 1.f;
        Cl[r * 256 + c] = f2bf(o);
      }
  __syncthreads();
  // epilogue phase 2: coalesced stores
  #pragma unroll
  for (int it = 0; it < 16; it++) {
    int idx = it * 512 + tid;
    int r = idx >> 5, c8 = (idx & 31) * 8;
    int gc = n0 + c8;
    ushort8v v = *reinterpret_cast<const ushort8v*>(&Cl[r * 256 + c8]);
    unsigned short* orow = otmp + (long)(m0 + r) * 2 * VOCAB;
    if (gc + 8 <= VOCAB) {
      *reinterpret_cast<ushort8v*>(orow + gc) = v;
    } else {
      #pragma unroll
      for (int e = 0; e < 8; e++)
        if (gc + e < VOCAB) orow[gc + e] = v[e];
    }
  }
}

// ---------------- kernel 6: in-place bf16 -> (fp32 - lse) with in-block lse ----------------
__global__ __launch_bounds__(1024) void k_sub(float* __restrict__ out) {
  int row = blockIdx.x;
  float* rb = out + (long)row * VOCAB;
  const unsigned int* src = reinterpret_cast<const unsigned int*>(rb);
  int tid = threadIdx.x;
  unsigned int v[15];
  float se = 0.f;
  #pragma unroll
  for (int i = 0; i < 15; i++) {
    int p = tid + i * 1024;
    v[i] = (p < VOCAB / 2) ? src[p] : 0u;
  }
  #pragma unroll
  for (int i = 0; i < 15; i++) {
    int p = tid + i * 1024;
    if (p < VOCAB / 2) {
      unsigned int u = v[i];
      float lo = __uint_as_float((u & 0xffffu) << 16);
      float hi = __uint_as_float(u & 0xffff0000u);
      se += __expf(lo) + __expf(hi);
    }
  }
  #pragma unroll
  for (int off = 32; off; off >>= 1) se += __shfl_xor(se, off);
  __shared__ float red[16];
  int wid = tid >> 6;
  if ((tid & 63) == 0) red[wid] = se;
  __syncthreads();
  if (tid < 16) {
    float r = red[tid];
    #pragma unroll
    for (int off = 8; off; off >>= 1) r += __shfl_xor(r, off);
    if (tid == 0) red[0] = logf(r);
  }
  __syncthreads();
  float L = red[0];
  floatx2* dst = reinterpret_cast<floatx2*>(rb);
  #pragma unroll
  for (int i = 0; i < 15; i++) {
    int p = tid + i * 1024;
    if (p < VOCAB / 2) {
      unsigned int u = v[i];
      float lo = __uint_as_float((u & 0xffffu) << 16);
      float hi = __uint_as_float(u & 0xffff0000u);
      floatx2 o; o.x = lo - L; o.y = hi - L;
      dst[p] = o;
    }
  }
}

extern "C" void kernel_launch(void* const* d_in, const int* in_sizes, int n_in,
                              void* d_out, int out_size, void* d_ws, size_t ws_size,
                              hipStream_t stream) {
  const int* tok = (const int*)d_in[0];
  const int* typ = (const int*)d_in[1];
  const int* syn = (const int*)d_in[2];
  const int* hw  = (const int*)d_in[3];
  const float* tok_emb  = (const float*)d_in[4];
  const float* type_emb = (const float*)d_in[5];
  const float* pos_emb  = (const float*)d_in[6];
  const float* ln_g = (const float*)d_in[7];
  const float* ln_b = (const float*)d_in[8];
  const float* W    = (const float*)d_in[9];
  const float* a    = (const float*)d_in[10];
  const float* out_W = (const float*)d_in[11];
  const float* out_b = (const float*)d_in[12];
  float* out = (float*)d_out;
  char* ws = (char*)d_ws;
  unsigned short* xb = (unsigned short*)(ws + 0);          // 2048*768*2 = 3145728
  float* Wh  = (float*)(ws + 3145728);                     // 4*2048*128*4 = 4194304
  float* e1  = (float*)(ws + 7340032);                     // 32768
  float* e2  = (float*)(ws + 7372800);                     // 32768
  float* cm  = (float*)(ws + 7405568);                     // 32768
  float* cs  = (float*)(ws + 7438336);                     // 32768
  unsigned short* cat = (unsigned short*)(ws + 7471104);   // 2048*512*2 = 2097152
  unsigned short* Wt  = (unsigned short*)(ws + 9568256);   // 512*768*2 = 786432
  unsigned short* owb = (unsigned short*)(ws + 10354688);  // VPAD*512*2 = 31457280

  k_prep<<<4120, 256, 0, stream>>>(out_W, owb, W, Wt, tok, typ,
                                   tok_emb, type_emb, pos_emb, ln_g, ln_b, xb);
  k_wh<<<64, 256, 0, stream>>>(xb, Wt, Wh);
  k_ecol<<<32, 256, 0, stream>>>(tok, typ, syn, hw, Wh, a, e1, e2, cm, cs);
  k_att<<<256, 256, 0, stream>>>(tok, typ, syn, hw, e1, e2, cm, cs, Wh, cat);
  k_gemm<<<8 * NT256, 512, 0, stream>>>(cat, owb, out_b, (unsigned short*)out);
  k_sub<<<2048, 1024, 0, stream>>>(out);
}